// Round 3
// baseline (2315.511 us; speedup 1.0000x reference)
//
#include <hip/hip_runtime.h>

typedef unsigned short ushort_t;
typedef short short8 __attribute__((ext_vector_type(8)));
typedef float float4v __attribute__((ext_vector_type(4)));

__device__ __forceinline__ float bf2f(ushort_t u) {
    union { unsigned int i; float f; } x; x.i = ((unsigned int)u) << 16; return x.f;
}
__device__ __forceinline__ ushort_t f2bf(float f) {
    unsigned int u = __float_as_uint(f);
    unsigned int r = (u + 0x7FFFu + ((u >> 16) & 1u)) >> 16;
    return (ushort_t)r;
}

__device__ __forceinline__ void store_out(float* p, float v) { *p = v; }
__device__ __forceinline__ void store_out(ushort_t* p, float v) { *p = f2bf(v); }

// ---------------------------------------------------------------------------
// Input-dtype detection. flag=1 -> inputs are bf16; flag=0 -> inputs are f32.
// bf16 N(0,1) data: every ushort has a sane exponent field (~512/512 pass).
// f32 data read as ushorts: even indices are mantissa-low bits with uniform
// "exponent" field (~16% pass) -> total ~297/512. Threshold 480 separates.
// ---------------------------------------------------------------------------
__global__ void detect_dtype(const ushort_t* __restrict__ tgt, int* __restrict__ flag) {
    __shared__ int red[256];
    const int tid = threadIdx.x;
    int p = 0;
    for (int i = tid; i < 512; i += 256) {
        ushort_t u = tgt[i];
        int e = (u >> 7) & 0xFF;
        if (u == 0 || (e >= 100 && e <= 140)) ++p;
    }
    red[tid] = p; __syncthreads();
    for (int off = 128; off > 0; off >>= 1) {
        if (tid < off) red[tid] += red[tid + off];
        __syncthreads();
    }
    if (tid == 0) flag[0] = (red[0] >= 480) ? 1 : 0;
}

// ---------------------------------------------------------------------------
// GEMM: C[M][N] = act(A[M][K] @ W[K][N] + bias)  (or C += A@W when ACCUM).
// 64x64 tile, BK=32, mfma_f32_16x16x32_bf16, 4 waves; W transposed into LDS
// [n][k]. W/bias are ALWAYS external inputs (dtype per flag); A is external
// only when A_EXT (otherwise internal bf16). wrow0/wcol0: element offsets
// into W/bias applied after the dtype cast (dtype-safe chunking).
// ---------------------------------------------------------------------------
template<typename OutT, bool RELU, bool ACCUM, bool A_EXT>
__global__ __launch_bounds__(256) void gemm_bt(
    const void* __restrict__ A, int lda,
    const void* __restrict__ W, int ldw, int wrow0, int wcol0,
    const void* __restrict__ bias,
    OutT* __restrict__ C, int ldc,
    int M, int N, int K, const int* __restrict__ dflag)
{
    __shared__ ushort_t As[64][32];   // [m][k]
    __shared__ ushort_t Bs[64][32];   // [n][k]  (transposed W tile)
    const bool extf32 = (dflag[0] == 0);
    const int tid  = threadIdx.x;
    const int wave = tid >> 6, lane = tid & 63;
    const int quad = lane >> 4, l16 = lane & 15;
    const int m0 = blockIdx.x * 64, n0 = blockIdx.y * 64;

    float4v acc[4];
#pragma unroll
    for (int i = 0; i < 4; ++i) { acc[i][0] = 0.f; acc[i][1] = 0.f; acc[i][2] = 0.f; acc[i][3] = 0.f; }

    const int am = tid >> 2, akk = (tid & 3) * 8;   // A: 8 contig k per thread
    const int bk = tid & 31, bn8 = (tid >> 5) * 8;  // W: 8 contig n per thread at row k

    for (int k0 = 0; k0 < K; k0 += 32) {
        // ---- A stage ----
        const size_t aidx = (size_t)(m0 + am) * lda + (k0 + akk);
        if (A_EXT && extf32) {
            const float* Af = (const float*)A;
            float4 f0 = *(const float4*)(Af + aidx);
            float4 f1 = *(const float4*)(Af + aidx + 4);
            uint4 pk;
            pk.x = (unsigned)f2bf(f0.x) | ((unsigned)f2bf(f0.y) << 16);
            pk.y = (unsigned)f2bf(f0.z) | ((unsigned)f2bf(f0.w) << 16);
            pk.z = (unsigned)f2bf(f1.x) | ((unsigned)f2bf(f1.y) << 16);
            pk.w = (unsigned)f2bf(f1.z) | ((unsigned)f2bf(f1.w) << 16);
            *(uint4*)(&As[am][akk]) = pk;
        } else {
            *(uint4*)(&As[am][akk]) = *(const uint4*)((const ushort_t*)A + aidx);
        }
        // ---- W stage (always external) ----
        const size_t widx = (size_t)(wrow0 + k0 + bk) * ldw + (wcol0 + n0 + bn8);
        ushort_t wv[8];
        if (extf32) {
            const float* Wf = (const float*)W;
            float4 g0 = *(const float4*)(Wf + widx);
            float4 g1 = *(const float4*)(Wf + widx + 4);
            wv[0] = f2bf(g0.x); wv[1] = f2bf(g0.y); wv[2] = f2bf(g0.z); wv[3] = f2bf(g0.w);
            wv[4] = f2bf(g1.x); wv[5] = f2bf(g1.y); wv[6] = f2bf(g1.z); wv[7] = f2bf(g1.w);
        } else {
            uint4 bvv = *(const uint4*)((const ushort_t*)W + widx);
            const ushort_t* be = (const ushort_t*)&bvv;
#pragma unroll
            for (int j = 0; j < 8; ++j) wv[j] = be[j];
        }
#pragma unroll
        for (int j = 0; j < 8; ++j) Bs[bn8 + j][bk] = wv[j];
        __syncthreads();

        short8 a = *(const short8*)(&As[wave * 16 + l16][quad * 8]);
#pragma unroll
        for (int ns = 0; ns < 4; ++ns) {
            short8 b = *(const short8*)(&Bs[ns * 16 + l16][quad * 8]);
            acc[ns] = __builtin_amdgcn_mfma_f32_16x16x32_bf16(a, b, acc[ns], 0, 0, 0);
        }
        __syncthreads();
    }

#pragma unroll
    for (int ns = 0; ns < 4; ++ns) {
        const int col = n0 + ns * 16 + l16;
        float bvv = 0.f;
        if (!ACCUM)
            bvv = extf32 ? ((const float*)bias)[wcol0 + col]
                         : bf2f(((const ushort_t*)bias)[wcol0 + col]);
#pragma unroll
        for (int r = 0; r < 4; ++r) {
            const int row = m0 + wave * 16 + quad * 4 + r;
            float v = acc[ns][r] + bvv;
            if (ACCUM) v += ((const float*)C)[(size_t)row * ldc + col];
            if (RELU) v = fmaxf(v, 0.f);
            store_out(&C[(size_t)row * ldc + col], v);
        }
    }
}

// ---------------------------------------------------------------------------
// Attention: one block = one (b,h) x 4 query rows. Two-pass softmax, scores
// in LDS. Q/K/V are internal bf16 [4096][512], head at col h*64. O aliases Q
// safely: each block reads only its own 4x64 Q sub-block (into LDS) and
// writes O to exactly that sub-block; sub-blocks are block-disjoint.
// ---------------------------------------------------------------------------
__global__ __launch_bounds__(256) void attn_kernel(
    const ushort_t* __restrict__ Q, const ushort_t* __restrict__ Kb,
    const ushort_t* __restrict__ Vb, ushort_t* __restrict__ O)
{
    const int E = 512;
    __shared__ float Qs[4][64];
    __shared__ float Ps[4][1024];
    __shared__ float red[256];
    __shared__ float Osum[4][4][64];

    const int tid = threadIdx.x;
    const int blk = blockIdx.x;
    const int t0 = (blk & 255) * 4;
    const int bh = blk >> 8;
    const int b = bh >> 3, h = bh & 7;
    const size_t qbase  = ((size_t)(b * 1024 + t0)) * E + h * 64;
    const size_t kvbase = ((size_t)(b * 1024)) * E + h * 64;

    {
        int q = tid >> 6, d = tid & 63;
        Qs[q][d] = 0.125f * bf2f(Q[qbase + (size_t)q * E + d]);
    }
    __syncthreads();

    for (int ss = 0; ss < 4; ++ss) {
        int s = tid + ss * 256;
        const ushort_t* kr = Kb + kvbase + (size_t)s * E;
        float a0 = 0.f, a1 = 0.f, a2 = 0.f, a3 = 0.f;
#pragma unroll
        for (int d8 = 0; d8 < 64; d8 += 8) {
            uint4 kv = *(const uint4*)(kr + d8);
            const ushort_t* ke = (const ushort_t*)&kv;
#pragma unroll
            for (int j = 0; j < 8; ++j) {
                float kf = bf2f(ke[j]);
                a0 += Qs[0][d8 + j] * kf; a1 += Qs[1][d8 + j] * kf;
                a2 += Qs[2][d8 + j] * kf; a3 += Qs[3][d8 + j] * kf;
            }
        }
        Ps[0][s] = a0; Ps[1][s] = a1; Ps[2][s] = a2; Ps[3][s] = a3;
    }
    __syncthreads();

    float linv[4];
    for (int q = 0; q < 4; ++q) {
        float lm = -1e30f;
        for (int ss = 0; ss < 4; ++ss) lm = fmaxf(lm, Ps[q][tid + ss * 256]);
        red[tid] = lm; __syncthreads();
        for (int off = 128; off > 0; off >>= 1) {
            if (tid < off) red[tid] = fmaxf(red[tid], red[tid + off]);
            __syncthreads();
        }
        float m = red[0]; __syncthreads();
        float ls = 0.f;
        for (int ss = 0; ss < 4; ++ss) {
            float p = __expf(Ps[q][tid + ss * 256] - m);
            Ps[q][tid + ss * 256] = p; ls += p;
        }
        red[tid] = ls; __syncthreads();
        for (int off = 128; off > 0; off >>= 1) {
            if (tid < off) red[tid] += red[tid + off];
            __syncthreads();
        }
        linv[q] = 1.f / red[0]; __syncthreads();
    }

    {
        const int w = tid >> 6, lane = tid & 63;
        float o0 = 0.f, o1 = 0.f, o2 = 0.f, o3 = 0.f;
        const int s0 = w * 256;
        for (int s = s0; s < s0 + 256; ++s) {
            float v = bf2f(Vb[kvbase + (size_t)s * E + lane]);
            o0 += Ps[0][s] * v; o1 += Ps[1][s] * v;
            o2 += Ps[2][s] * v; o3 += Ps[3][s] * v;
        }
        Osum[w][0][lane] = o0; Osum[w][1][lane] = o1;
        Osum[w][2][lane] = o2; Osum[w][3][lane] = o3;
    }
    __syncthreads();
    if (tid < 64) {
#pragma unroll
        for (int q = 0; q < 4; ++q) {
            float t = Osum[0][q][tid] + Osum[1][q][tid] + Osum[2][q][tid] + Osum[3][q][tid];
            O[qbase + (size_t)q * E + tid] = f2bf(t * linv[q]);
        }
    }
}

// ---------------------------------------------------------------------------
// LayerNorm over E=512: x = res + delta; out = (x-mu)*rstd*g + b.
// res: external (flag dtype) if RES_EXT else internal bf16.
// delta: internal, f32 if DELTA_F32 else bf16. g/be: external (flag dtype).
// out: if OUT_FLAG, dtype per flag (final output); else internal bf16.
// Safe to have out alias res: block reads its row before writing it.
// ---------------------------------------------------------------------------
template<bool RES_EXT, bool DELTA_F32, bool OUT_FLAG>
__global__ __launch_bounds__(256) void ln_kernel(
    const void* __restrict__ res, const void* __restrict__ delta,
    const void* __restrict__ g, const void* __restrict__ be,
    void* __restrict__ out, const int* __restrict__ dflag)
{
    const int E = 512;
    const bool extf32 = (dflag[0] == 0);
    const int row = blockIdx.x, tid = threadIdx.x;
    const size_t base = (size_t)row * E;
    const int i0 = tid, i1 = tid + 256;

    float r0, r1;
    if (RES_EXT && extf32) {
        r0 = ((const float*)res)[base + i0];
        r1 = ((const float*)res)[base + i1];
    } else {
        r0 = bf2f(((const ushort_t*)res)[base + i0]);
        r1 = bf2f(((const ushort_t*)res)[base + i1]);
    }
    float d0v, d1v;
    if (DELTA_F32) {
        d0v = ((const float*)delta)[base + i0];
        d1v = ((const float*)delta)[base + i1];
    } else {
        d0v = bf2f(((const ushort_t*)delta)[base + i0]);
        d1v = bf2f(((const ushort_t*)delta)[base + i1]);
    }
    float x0 = r0 + d0v, x1 = r1 + d1v;

    __shared__ float red[256];
    red[tid] = x0 + x1; __syncthreads();
    for (int off = 128; off > 0; off >>= 1) {
        if (tid < off) red[tid] += red[tid + off];
        __syncthreads();
    }
    float mean = red[0] * (1.0f / 512.0f); __syncthreads();
    float dd0 = x0 - mean, dd1 = x1 - mean;
    red[tid] = dd0 * dd0 + dd1 * dd1; __syncthreads();
    for (int off = 128; off > 0; off >>= 1) {
        if (tid < off) red[tid] += red[tid + off];
        __syncthreads();
    }
    float rstd = rsqrtf(red[0] * (1.0f / 512.0f) + 1e-5f);

    float g0, g1v, b0, b1;
    if (extf32) {
        g0 = ((const float*)g)[i0];  g1v = ((const float*)g)[i1];
        b0 = ((const float*)be)[i0]; b1  = ((const float*)be)[i1];
    } else {
        g0 = bf2f(((const ushort_t*)g)[i0]);  g1v = bf2f(((const ushort_t*)g)[i1]);
        b0 = bf2f(((const ushort_t*)be)[i0]); b1  = bf2f(((const ushort_t*)be)[i1]);
    }
    float y0 = dd0 * rstd * g0 + b0;
    float y1 = dd1 * rstd * g1v + b1;
    if (OUT_FLAG && extf32) {
        ((float*)out)[base + i0] = y0; ((float*)out)[base + i1] = y1;
    } else {
        ((ushort_t*)out)[base + i0] = f2bf(y0);
        ((ushort_t*)out)[base + i1] = f2bf(y1);
    }
}

// ---------------------------------------------------------------------------
// Workspace (20 MiB + flag page):
//   [ 0 .. 4M)  qb   bf16  Q; attn O in-place;  FFN hc low half
//   [ 4M.. 8M)  kb   bf16  K;                   FFN hc high half
//   [ 8M..12M)  vb   bf16  V;                   FFN of f32 low half
//   [12M..16M)  po   bf16  proj delta;          FFN of f32 high half
//   [16M..20M)  xb   bf16  residual stream / LN output (GEMM input)
//   [20M]       dflag int
// ---------------------------------------------------------------------------

extern "C" void kernel_launch(void* const* d_in, const int* in_sizes, int n_in,
                              void* d_out, int out_size, void* d_ws, size_t ws_size,
                              hipStream_t stream) {
    const void* tgt = d_in[0];
    const void* mem = d_in[1];
    const void* sWq = d_in[2];  const void* sWk = d_in[3];
    const void* sWv = d_in[4];  const void* sWo = d_in[5];
    const void* cWq = d_in[6];  const void* cWk = d_in[7];
    const void* cWv = d_in[8];  const void* cWo = d_in[9];
    const void* sbq = d_in[10]; const void* sbk = d_in[11];
    const void* sbv = d_in[12]; const void* sbo = d_in[13];
    const void* cbq = d_in[14]; const void* cbk = d_in[15];
    const void* cbv = d_in[16]; const void* cbo = d_in[17];
    const void* fW1 = d_in[18]; const void* fb1 = d_in[19];
    const void* fW2 = d_in[20]; const void* fb2 = d_in[21];
    const void* g1  = d_in[22]; const void* g2  = d_in[23];
    const void* g3  = d_in[24];
    const void* be1 = d_in[25]; const void* be2 = d_in[26];
    const void* be3 = d_in[27];

    char* ws = (char*)d_ws;
    const size_t MB = 1048576;
    ushort_t* qb = (ushort_t*)(ws + 0 * MB);
    ushort_t* kb = (ushort_t*)(ws + 4 * MB);
    ushort_t* vb = (ushort_t*)(ws + 8 * MB);
    ushort_t* po = (ushort_t*)(ws + 12 * MB);
    ushort_t* xb = (ushort_t*)(ws + 16 * MB);
    int*   dflag = (int*)    (ws + 20 * MB);
    ushort_t* hc = (ushort_t*)(ws + 0 * MB);   // FFN hidden chunk [4096][1024] bf16
    float*    of = (float*)   (ws + 8 * MB);   // FFN out accum [4096][512] f32

    hipMemsetAsync(d_ws, 0, 20 * MB + 4096, stream);
    detect_dtype<<<dim3(1), dim3(256), 0, stream>>>((const ushort_t*)tgt, dflag);

    const int M = 4096;
    dim3 blk(256);
    dim3 g512(64, 8), g1024(64, 16);

    // ---- self-attention ----
    gemm_bt<ushort_t, false, false, true ><<<g512, blk, 0, stream>>>(tgt, 512, sWq, 512, 0, 0, sbq, qb, 512, M, 512, 512, dflag);
    gemm_bt<ushort_t, false, false, true ><<<g512, blk, 0, stream>>>(tgt, 512, sWk, 512, 0, 0, sbk, kb, 512, M, 512, 512, dflag);
    gemm_bt<ushort_t, false, false, true ><<<g512, blk, 0, stream>>>(tgt, 512, sWv, 512, 0, 0, sbv, vb, 512, M, 512, 512, dflag);
    attn_kernel<<<dim3(8192), blk, 0, stream>>>(qb, kb, vb, qb);
    gemm_bt<ushort_t, false, false, false><<<g512, blk, 0, stream>>>(qb, 512, sWo, 512, 0, 0, sbo, po, 512, M, 512, 512, dflag);
    ln_kernel<true, false, false><<<dim3(4096), blk, 0, stream>>>(tgt, po, g1, be1, xb, dflag);

    // ---- cross-attention ----
    gemm_bt<ushort_t, false, false, false><<<g512, blk, 0, stream>>>(xb,  512, cWq, 512, 0, 0, cbq, qb, 512, M, 512, 512, dflag);
    gemm_bt<ushort_t, false, false, true ><<<g512, blk, 0, stream>>>(mem, 512, cWk, 512, 0, 0, cbk, kb, 512, M, 512, 512, dflag);
    gemm_bt<ushort_t, false, false, true ><<<g512, blk, 0, stream>>>(mem, 512, cWv, 512, 0, 0, cbv, vb, 512, M, 512, 512, dflag);
    attn_kernel<<<dim3(8192), blk, 0, stream>>>(qb, kb, vb, qb);
    gemm_bt<ushort_t, false, false, false><<<g512, blk, 0, stream>>>(qb, 512, cWo, 512, 0, 0, cbo, po, 512, M, 512, 512, dflag);
    ln_kernel<false, false, false><<<dim3(4096), blk, 0, stream>>>(xb, po, g2, be2, xb, dflag);

    // ---- FFN: two K-chunks of 1024 over F=2048, f32 accumulation in `of` ----
    gemm_bt<ushort_t, true, false, false><<<g1024, blk, 0, stream>>>(xb, 512, fW1, 2048, 0, 0,    fb1, hc, 1024, M, 1024, 512, dflag);
    gemm_bt<float, false, false, false ><<<g512,  blk, 0, stream>>>(hc, 1024, fW2, 512,  0, 0,    fb2, of, 512,  M, 512, 1024, dflag);
    gemm_bt<ushort_t, true, false, false><<<g1024, blk, 0, stream>>>(xb, 512, fW1, 2048, 0, 1024, fb1, hc, 1024, M, 1024, 512, dflag);
    gemm_bt<float, false, true, false  ><<<g512,  blk, 0, stream>>>(hc, 1024, fW2, 512,  1024, 0, fb2, of, 512,  M, 512, 1024, dflag);
    ln_kernel<false, true, true><<<dim3(4096), blk, 0, stream>>>(xb, of, g3, be3, d_out, dflag);
}

// Round 5
// 545.246 us; speedup vs baseline: 4.2467x; 4.2467x over previous
//
#include <hip/hip_runtime.h>

typedef unsigned short ushort_t;
typedef short short8 __attribute__((ext_vector_type(8)));
typedef float float4v __attribute__((ext_vector_type(4)));

__device__ __forceinline__ float bf2f(ushort_t u) {
    union { unsigned int i; float f; } x; x.i = ((unsigned int)u) << 16; return x.f;
}
__device__ __forceinline__ ushort_t f2bf(float f) {
    unsigned int u = __float_as_uint(f);
    unsigned int r = (u + 0x7FFFu + ((u >> 16) & 1u)) >> 16;
    return (ushort_t)r;
}

__device__ __forceinline__ void store_out(float* p, float v) { *p = v; }
__device__ __forceinline__ void store_out(ushort_t* p, float v) { *p = f2bf(v); }

// ---------------------------------------------------------------------------
// Input-dtype detection. flag=1 -> inputs bf16; flag=0 -> inputs f32.
// ---------------------------------------------------------------------------
__global__ void detect_dtype(const ushort_t* __restrict__ tgt, int* __restrict__ flag) {
    __shared__ int red[256];
    const int tid = threadIdx.x;
    int p = 0;
    for (int i = tid; i < 512; i += 256) {
        ushort_t u = tgt[i];
        int e = (u >> 7) & 0xFF;
        if (u == 0 || (e >= 100 && e <= 140)) ++p;
    }
    red[tid] = p; __syncthreads();
    for (int off = 128; off > 0; off >>= 1) {
        if (tid < off) red[tid] += red[tid + off];
        __syncthreads();
    }
    if (tid == 0) flag[0] = (red[0] >= 480) ? 1 : 0;
}

// ---------------------------------------------------------------------------
// GEMM: C[M][N] = act(A[M][K] @ W[K][N] + bias)  (or C += A@W when ACCUM).
// 64x64 tile, BK=32, mfma_f32_16x16x32_bf16. Unchanged from round 3 (passed).
// ---------------------------------------------------------------------------
template<typename OutT, bool RELU, bool ACCUM, bool A_EXT>
__global__ __launch_bounds__(256) void gemm_bt(
    const void* __restrict__ A, int lda,
    const void* __restrict__ W, int ldw, int wrow0, int wcol0,
    const void* __restrict__ bias,
    OutT* __restrict__ C, int ldc,
    int M, int N, int K, const int* __restrict__ dflag)
{
    __shared__ ushort_t As[64][32];   // [m][k]
    __shared__ ushort_t Bs[64][32];   // [n][k]  (transposed W tile)
    const bool extf32 = (dflag[0] == 0);
    const int tid  = threadIdx.x;
    const int wave = tid >> 6, lane = tid & 63;
    const int quad = lane >> 4, l16 = lane & 15;
    const int m0 = blockIdx.x * 64, n0 = blockIdx.y * 64;

    float4v acc[4];
#pragma unroll
    for (int i = 0; i < 4; ++i) { acc[i][0] = 0.f; acc[i][1] = 0.f; acc[i][2] = 0.f; acc[i][3] = 0.f; }

    const int am = tid >> 2, akk = (tid & 3) * 8;
    const int bk = tid & 31, bn8 = (tid >> 5) * 8;

    for (int k0 = 0; k0 < K; k0 += 32) {
        const size_t aidx = (size_t)(m0 + am) * lda + (k0 + akk);
        if (A_EXT && extf32) {
            const float* Af = (const float*)A;
            float4 f0 = *(const float4*)(Af + aidx);
            float4 f1 = *(const float4*)(Af + aidx + 4);
            uint4 pk;
            pk.x = (unsigned)f2bf(f0.x) | ((unsigned)f2bf(f0.y) << 16);
            pk.y = (unsigned)f2bf(f0.z) | ((unsigned)f2bf(f0.w) << 16);
            pk.z = (unsigned)f2bf(f1.x) | ((unsigned)f2bf(f1.y) << 16);
            pk.w = (unsigned)f2bf(f1.z) | ((unsigned)f2bf(f1.w) << 16);
            *(uint4*)(&As[am][akk]) = pk;
        } else {
            *(uint4*)(&As[am][akk]) = *(const uint4*)((const ushort_t*)A + aidx);
        }
        const size_t widx = (size_t)(wrow0 + k0 + bk) * ldw + (wcol0 + n0 + bn8);
        ushort_t wv[8];
        if (extf32) {
            const float* Wf = (const float*)W;
            float4 g0 = *(const float4*)(Wf + widx);
            float4 g1 = *(const float4*)(Wf + widx + 4);
            wv[0] = f2bf(g0.x); wv[1] = f2bf(g0.y); wv[2] = f2bf(g0.z); wv[3] = f2bf(g0.w);
            wv[4] = f2bf(g1.x); wv[5] = f2bf(g1.y); wv[6] = f2bf(g1.z); wv[7] = f2bf(g1.w);
        } else {
            uint4 bvv = *(const uint4*)((const ushort_t*)W + widx);
            const ushort_t* be = (const ushort_t*)&bvv;
#pragma unroll
            for (int j = 0; j < 8; ++j) wv[j] = be[j];
        }
#pragma unroll
        for (int j = 0; j < 8; ++j) Bs[bn8 + j][bk] = wv[j];
        __syncthreads();

        short8 a = *(const short8*)(&As[wave * 16 + l16][quad * 8]);
#pragma unroll
        for (int ns = 0; ns < 4; ++ns) {
            short8 b = *(const short8*)(&Bs[ns * 16 + l16][quad * 8]);
            acc[ns] = __builtin_amdgcn_mfma_f32_16x16x32_bf16(a, b, acc[ns], 0, 0, 0);
        }
        __syncthreads();
    }

#pragma unroll
    for (int ns = 0; ns < 4; ++ns) {
        const int col = n0 + ns * 16 + l16;
        float bvv = 0.f;
        if (!ACCUM)
            bvv = extf32 ? ((const float*)bias)[wcol0 + col]
                         : bf2f(((const ushort_t*)bias)[wcol0 + col]);
#pragma unroll
        for (int r = 0; r < 4; ++r) {
            const int row = m0 + wave * 16 + quad * 4 + r;
            float v = acc[ns][r] + bvv;
            if (ACCUM) v += ((const float*)C)[(size_t)row * ldc + col];
            if (RELU) v = fmaxf(v, 0.f);
            store_out(&C[(size_t)row * ldc + col], v);
        }
    }
}

// ---------------------------------------------------------------------------
// Flash attention (MFMA). Block = 64 q-rows of one (b,h); 4 waves x 16 rows.
// S-tiles of 64: K staged [s][d], V transposed [d][s] with 8-chunk XOR
// swizzle; QK^T and PV via mfma_f32_16x16x32_bf16; online softmax in raw
// score domain (scale folded into exp2 constant); P round-trips through LDS
// (C-layout -> A-operand layout, m120-verified). O may alias Q: block reads
// only its own 64-row Q tile (staged before loop) and writes exactly that
// tile at the end; tiles are block-disjoint.
// ---------------------------------------------------------------------------
__global__ __launch_bounds__(256) void attn_mfma(
    const ushort_t* __restrict__ Q, const ushort_t* __restrict__ Kb,
    const ushort_t* __restrict__ Vb, ushort_t* __restrict__ O)
{
    const int E = 512;
    __shared__ ushort_t Qs[64][72];
    __shared__ ushort_t Ks[64][72];
    __shared__ ushort_t Vt[64][72];      // [d][s swizzled in 8-chunks]
    __shared__ ushort_t Ps[4][16][72];   // per-wave P tile [q][s]

    const int tid  = threadIdx.x;
    const int wave = tid >> 6, lane = tid & 63;
    const int quad = lane >> 4, l16 = lane & 15;
    const int qt = blockIdx.x, bh = blockIdx.y;
    const int b = bh >> 3, h = bh & 7;
    const size_t rowQ = (size_t)b * 1024 + qt * 64;   // global q-row base
    const size_t kv0  = (size_t)b * 1024;

    // stage Q tile (64 x 64)
    {
        const int r = tid >> 2, c = (tid & 3) * 16;
        const ushort_t* src = Q + (rowQ + r) * E + h * 64 + c;
        *(uint4*)(&Qs[r][c])     = *(const uint4*)(src);
        *(uint4*)(&Qs[r][c + 8]) = *(const uint4*)(src + 8);
    }
    __syncthreads();
    short8 qf[2];
    qf[0] = *(const short8*)(&Qs[wave * 16 + l16][quad * 8]);
    qf[1] = *(const short8*)(&Qs[wave * 16 + l16][32 + quad * 8]);

    const float CEXP = 0.125f * 1.44269504f;  // head-scale * log2(e)
    float m_i[4], l_i[4];
    float4v oacc[4];
#pragma unroll
    for (int r = 0; r < 4; ++r) { m_i[r] = -1e30f; l_i[r] = 0.f; }
#pragma unroll
    for (int n = 0; n < 4; ++n) { oacc[n][0]=0.f; oacc[n][1]=0.f; oacc[n][2]=0.f; oacc[n][3]=0.f; }

    for (int s0 = 0; s0 < 1024; s0 += 64) {
        __syncthreads();   // prior iteration's frag reads done
        {  // stage K (direct) and V (transposed + swizzled)
            const int r = tid >> 2, c = (tid & 3) * 16;
            const ushort_t* ksrc = Kb + (kv0 + s0 + r) * E + h * 64 + c;
            *(uint4*)(&Ks[r][c])     = *(const uint4*)(ksrc);
            *(uint4*)(&Ks[r][c + 8]) = *(const uint4*)(ksrc + 8);
            const ushort_t* vsrc = Vb + (kv0 + s0 + r) * E + h * 64 + c;
            ushort_t ve[16];
            *(uint4*)(&ve[0]) = *(const uint4*)(vsrc);
            *(uint4*)(&ve[8]) = *(const uint4*)(vsrc + 8);
#pragma unroll
            for (int j = 0; j < 16; ++j) {
                const int d = c + j;
                const int cc = ((r >> 3) ^ (d >> 4)) & 7;
                Vt[d][cc * 8 + (r & 7)] = ve[j];
            }
        }
        __syncthreads();

        // QK^T: 4 s-chunks of 16, K-dim 64 in 2 MFMAs
        float4v sc[4];
#pragma unroll
        for (int sb = 0; sb < 4; ++sb) {
            float4v z; z[0]=0.f; z[1]=0.f; z[2]=0.f; z[3]=0.f;
            short8 kf0 = *(const short8*)(&Ks[sb * 16 + l16][quad * 8]);
            short8 kf1 = *(const short8*)(&Ks[sb * 16 + l16][32 + quad * 8]);
            z = __builtin_amdgcn_mfma_f32_16x16x32_bf16(qf[0], kf0, z, 0, 0, 0);
            z = __builtin_amdgcn_mfma_f32_16x16x32_bf16(qf[1], kf1, z, 0, 0, 0);
            sc[sb] = z;
        }

        // online softmax (raw-score domain)
        float mt[4], al[4], rs[4];
#pragma unroll
        for (int r = 0; r < 4; ++r)
            mt[r] = fmaxf(fmaxf(sc[0][r], sc[1][r]), fmaxf(sc[2][r], sc[3][r]));
#pragma unroll
        for (int msk = 1; msk < 16; msk <<= 1)
#pragma unroll
            for (int r = 0; r < 4; ++r) mt[r] = fmaxf(mt[r], __shfl_xor(mt[r], msk));
#pragma unroll
        for (int r = 0; r < 4; ++r) {
            float mn = fmaxf(m_i[r], mt[r]);
            al[r] = exp2f((m_i[r] - mn) * CEXP);
            m_i[r] = mn; rs[r] = 0.f;
        }
#pragma unroll
        for (int sb = 0; sb < 4; ++sb)
#pragma unroll
            for (int r = 0; r < 4; ++r) {
                float p = exp2f((sc[sb][r] - m_i[r]) * CEXP);
                rs[r] += p;
                Ps[wave][quad * 4 + r][sb * 16 + l16] = f2bf(p);
            }
#pragma unroll
        for (int msk = 1; msk < 16; msk <<= 1)
#pragma unroll
            for (int r = 0; r < 4; ++r) rs[r] += __shfl_xor(rs[r], msk);
#pragma unroll
        for (int r = 0; r < 4; ++r) l_i[r] = l_i[r] * al[r] + rs[r];
#pragma unroll
        for (int n = 0; n < 4; ++n)
#pragma unroll
            for (int r = 0; r < 4; ++r) oacc[n][r] *= al[r];

        // PV: A = P (LDS round-trip), B = Vt
        short8 pf[2];
        pf[0] = *(const short8*)(&Ps[wave][l16][quad * 8]);
        pf[1] = *(const short8*)(&Ps[wave][l16][32 + quad * 8]);
#pragma unroll
        for (int n = 0; n < 4; ++n) {
#pragma unroll
            for (int kc = 0; kc < 2; ++kc) {
                const int cc = ((kc * 4 + quad) ^ n) & 7;
                short8 vf = *(const short8*)(&Vt[n * 16 + l16][cc * 8]);
                oacc[n] = __builtin_amdgcn_mfma_f32_16x16x32_bf16(pf[kc], vf, oacc[n], 0, 0, 0);
            }
        }
    }

    // epilogue: O = acc / l
    float inv[4];
#pragma unroll
    for (int r = 0; r < 4; ++r) inv[r] = 1.f / l_i[r];
#pragma unroll
    for (int n = 0; n < 4; ++n)
#pragma unroll
        for (int r = 0; r < 4; ++r) {
            const size_t row = rowQ + wave * 16 + quad * 4 + r;
            O[row * E + h * 64 + n * 16 + l16] = f2bf(oacc[n][r] * inv[r]);
        }
}

// ---------------------------------------------------------------------------
// LayerNorm over E=512. Unchanged from round 3 (passed).
// ---------------------------------------------------------------------------
template<bool RES_EXT, bool DELTA_F32, bool OUT_FLAG>
__global__ __launch_bounds__(256) void ln_kernel(
    const void* __restrict__ res, const void* __restrict__ delta,
    const void* __restrict__ g, const void* __restrict__ be,
    void* __restrict__ out, const int* __restrict__ dflag)
{
    const int E = 512;
    const bool extf32 = (dflag[0] == 0);
    const int row = blockIdx.x, tid = threadIdx.x;
    const size_t base = (size_t)row * E;
    const int i0 = tid, i1 = tid + 256;

    float r0, r1;
    if (RES_EXT && extf32) {
        r0 = ((const float*)res)[base + i0];
        r1 = ((const float*)res)[base + i1];
    } else {
        r0 = bf2f(((const ushort_t*)res)[base + i0]);
        r1 = bf2f(((const ushort_t*)res)[base + i1]);
    }
    float d0v, d1v;
    if (DELTA_F32) {
        d0v = ((const float*)delta)[base + i0];
        d1v = ((const float*)delta)[base + i1];
    } else {
        d0v = bf2f(((const ushort_t*)delta)[base + i0]);
        d1v = bf2f(((const ushort_t*)delta)[base + i1]);
    }
    float x0 = r0 + d0v, x1 = r1 + d1v;

    __shared__ float red[256];
    red[tid] = x0 + x1; __syncthreads();
    for (int off = 128; off > 0; off >>= 1) {
        if (tid < off) red[tid] += red[tid + off];
        __syncthreads();
    }
    float mean = red[0] * (1.0f / 512.0f); __syncthreads();
    float dd0 = x0 - mean, dd1 = x1 - mean;
    red[tid] = dd0 * dd0 + dd1 * dd1; __syncthreads();
    for (int off = 128; off > 0; off >>= 1) {
        if (tid < off) red[tid] += red[tid + off];
        __syncthreads();
    }
    float rstd = rsqrtf(red[0] * (1.0f / 512.0f) + 1e-5f);

    float g0, g1v, b0, b1;
    if (extf32) {
        g0 = ((const float*)g)[i0];  g1v = ((const float*)g)[i1];
        b0 = ((const float*)be)[i0]; b1  = ((const float*)be)[i1];
    } else {
        g0 = bf2f(((const ushort_t*)g)[i0]);  g1v = bf2f(((const ushort_t*)g)[i1]);
        b0 = bf2f(((const ushort_t*)be)[i0]); b1  = bf2f(((const ushort_t*)be)[i1]);
    }
    float y0 = dd0 * rstd * g0 + b0;
    float y1 = dd1 * rstd * g1v + b1;
    if (OUT_FLAG && extf32) {
        ((float*)out)[base + i0] = y0; ((float*)out)[base + i1] = y1;
    } else {
        ((ushort_t*)out)[base + i0] = f2bf(y0);
        ((ushort_t*)out)[base + i1] = f2bf(y1);
    }
}

// ---------------------------------------------------------------------------
// Workspace (20 MiB + flag). All buffers write-before-read every call, so no
// memset needed despite 0xAA poisoning.
//   [ 0 .. 4M)  qb   Q / attn O in-place / FFN hc low
//   [ 4M.. 8M)  kb   K                  / FFN hc high
//   [ 8M..12M)  vb   V                  / FFN of f32 low
//   [12M..16M)  po   proj delta         / FFN of f32 high
//   [16M..20M)  xb   residual stream (bf16)
//   [20M]       dflag
// ---------------------------------------------------------------------------

extern "C" void kernel_launch(void* const* d_in, const int* in_sizes, int n_in,
                              void* d_out, int out_size, void* d_ws, size_t ws_size,
                              hipStream_t stream) {
    const void* tgt = d_in[0];
    const void* mem = d_in[1];
    const void* sWq = d_in[2];  const void* sWk = d_in[3];
    const void* sWv = d_in[4];  const void* sWo = d_in[5];
    const void* cWq = d_in[6];  const void* cWk = d_in[7];
    const void* cWv = d_in[8];  const void* cWo = d_in[9];
    const void* sbq = d_in[10]; const void* sbk = d_in[11];
    const void* sbv = d_in[12]; const void* sbo = d_in[13];
    const void* cbq = d_in[14]; const void* cbk = d_in[15];
    const void* cbv = d_in[16]; const void* cbo = d_in[17];
    const void* fW1 = d_in[18]; const void* fb1 = d_in[19];
    const void* fW2 = d_in[20]; const void* fb2 = d_in[21];
    const void* g1  = d_in[22]; const void* g2  = d_in[23];
    const void* g3  = d_in[24];
    const void* be1 = d_in[25]; const void* be2 = d_in[26];
    const void* be3 = d_in[27];

    char* ws = (char*)d_ws;
    const size_t MB = 1048576;
    ushort_t* qb = (ushort_t*)(ws + 0 * MB);
    ushort_t* kb = (ushort_t*)(ws + 4 * MB);
    ushort_t* vb = (ushort_t*)(ws + 8 * MB);
    ushort_t* po = (ushort_t*)(ws + 12 * MB);
    ushort_t* xb = (ushort_t*)(ws + 16 * MB);
    int*   dflag = (int*)    (ws + 20 * MB);
    ushort_t* hc = (ushort_t*)(ws + 0 * MB);   // FFN hidden chunk [4096][1024]
    float*    of = (float*)   (ws + 8 * MB);   // FFN out accum [4096][512] f32

    detect_dtype<<<dim3(1), dim3(256), 0, stream>>>((const ushort_t*)tgt, dflag);

    const int M = 4096;
    dim3 blk(256);
    dim3 g512(64, 8), g1024(64, 16), gattn(16, 32);

    // ---- self-attention ----
    gemm_bt<ushort_t, false, false, true ><<<g512, blk, 0, stream>>>(tgt, 512, sWq, 512, 0, 0, sbq, qb, 512, M, 512, 512, dflag);
    gemm_bt<ushort_t, false, false, true ><<<g512, blk, 0, stream>>>(tgt, 512, sWk, 512, 0, 0, sbk, kb, 512, M, 512, 512, dflag);
    gemm_bt<ushort_t, false, false, true ><<<g512, blk, 0, stream>>>(tgt, 512, sWv, 512, 0, 0, sbv, vb, 512, M, 512, 512, dflag);
    attn_mfma<<<gattn, blk, 0, stream>>>(qb, kb, vb, qb);
    gemm_bt<ushort_t, false, false, false><<<g512, blk, 0, stream>>>(qb, 512, sWo, 512, 0, 0, sbo, po, 512, M, 512, 512, dflag);
    ln_kernel<true, false, false><<<dim3(4096), blk, 0, stream>>>(tgt, po, g1, be1, xb, dflag);

    // ---- cross-attention ----
    gemm_bt<ushort_t, false, false, false><<<g512, blk, 0, stream>>>(xb,  512, cWq, 512, 0, 0, cbq, qb, 512, M, 512, 512, dflag);
    gemm_bt<ushort_t, false, false, true ><<<g512, blk, 0, stream>>>(mem, 512, cWk, 512, 0, 0, cbk, kb, 512, M, 512, 512, dflag);
    gemm_bt<ushort_t, false, false, true ><<<g512, blk, 0, stream>>>(mem, 512, cWv, 512, 0, 0, cbv, vb, 512, M, 512, 512, dflag);
    attn_mfma<<<gattn, blk, 0, stream>>>(qb, kb, vb, qb);
    gemm_bt<ushort_t, false, false, false><<<g512, blk, 0, stream>>>(qb, 512, cWo, 512, 0, 0, cbo, po, 512, M, 512, 512, dflag);
    ln_kernel<false, false, false><<<dim3(4096), blk, 0, stream>>>(xb, po, g2, be2, xb, dflag);

    // ---- FFN: two K-chunks of 1024 over F=2048, f32 accumulation in `of` ----
    gemm_bt<ushort_t, true, false, false><<<g1024, blk, 0, stream>>>(xb, 512, fW1, 2048, 0, 0,    fb1, hc, 1024, M, 1024, 512, dflag);
    gemm_bt<float, false, false, false ><<<g512,  blk, 0, stream>>>(hc, 1024, fW2, 512,  0, 0,    fb2, of, 512,  M, 512, 1024, dflag);
    gemm_bt<ushort_t, true, false, false><<<g1024, blk, 0, stream>>>(xb, 512, fW1, 2048, 0, 1024, fb1, hc, 1024, M, 1024, 512, dflag);
    gemm_bt<float, false, true, false  ><<<g512,  blk, 0, stream>>>(hc, 1024, fW2, 512,  1024, 0, fb2, of, 512,  M, 512, 1024, dflag);
    ln_kernel<false, true, true><<<dim3(4096), blk, 0, stream>>>(xb, of, g3, be3, d_out, dflag);
}

// Round 6
// 420.734 us; speedup vs baseline: 5.5035x; 1.2959x over previous
//
#include <hip/hip_runtime.h>

typedef unsigned short ushort_t;
typedef short short8 __attribute__((ext_vector_type(8)));
typedef float float4v __attribute__((ext_vector_type(4)));

__device__ __forceinline__ float bf2f(ushort_t u) {
    union { unsigned int i; float f; } x; x.i = ((unsigned int)u) << 16; return x.f;
}
__device__ __forceinline__ ushort_t f2bf(float f) {
    unsigned int u = __float_as_uint(f);
    unsigned int r = (u + 0x7FFFu + ((u >> 16) & 1u)) >> 16;
    return (ushort_t)r;
}
__device__ __forceinline__ void store_out(float* p, float v) { *p = v; }
__device__ __forceinline__ void store_out(ushort_t* p, float v) { *p = f2bf(v); }

// async global->LDS 16B/lane; lds ptr must be wave-uniform base (lane*16 auto)
__device__ __forceinline__ void gll16(const ushort_t* g, ushort_t* l) {
    __builtin_amdgcn_global_load_lds(
        (const __attribute__((address_space(1))) void*)g,
        (__attribute__((address_space(3))) void*)l, 16, 0, 0);
}

// ---------------------------------------------------------------------------
// Input-dtype detection. flag=1 -> inputs bf16; flag=0 -> inputs f32.
// ---------------------------------------------------------------------------
__global__ void detect_dtype(const ushort_t* __restrict__ tgt, int* __restrict__ flag) {
    __shared__ int red[256];
    const int tid = threadIdx.x;
    int p = 0;
    for (int i = tid; i < 512; i += 256) {
        ushort_t u = tgt[i];
        int e = (u >> 7) & 0xFF;
        if (u == 0 || (e >= 100 && e <= 140)) ++p;
    }
    red[tid] = p; __syncthreads();
    for (int off = 128; off > 0; off >>= 1) {
        if (tid < off) red[tid] += red[tid + off];
        __syncthreads();
    }
    if (tid == 0) flag[0] = (red[0] >= 480) ? 1 : 0;
}

// ---------------------------------------------------------------------------
// Weight prep: src[K][N] (ext dtype) -> dst[N][K] bf16, via 64x64 LDS tile.
// grid (32,32,10); z selects tensor; out-of-range tiles early-out.
// ---------------------------------------------------------------------------
__global__ __launch_bounds__(256) void wtrans_all(
    const void* sWq, const void* sWk, const void* sWv, const void* sWo,
    const void* cWq, const void* cWk, const void* cWv, const void* cWo,
    const void* fW1, const void* fW2,
    ushort_t* __restrict__ wb, const int* __restrict__ dflag)
{
    const void* src; ushort_t* dst; int Kd, Nd;
    switch (blockIdx.z) {
        case 0: src = sWq; dst = wb + 0;       Kd = 512;  Nd = 512;  break;
        case 1: src = sWk; dst = wb + 262144;  Kd = 512;  Nd = 512;  break;
        case 2: src = sWv; dst = wb + 524288;  Kd = 512;  Nd = 512;  break;
        case 3: src = sWo; dst = wb + 786432;  Kd = 512;  Nd = 512;  break;
        case 4: src = cWq; dst = wb + 1048576; Kd = 512;  Nd = 512;  break;
        case 5: src = cWk; dst = wb + 1310720; Kd = 512;  Nd = 512;  break;
        case 6: src = cWv; dst = wb + 1572864; Kd = 512;  Nd = 512;  break;
        case 7: src = cWo; dst = wb + 1835008; Kd = 512;  Nd = 512;  break;
        case 8: src = fW1; dst = wb + 2097152; Kd = 512;  Nd = 2048; break;
        default:src = fW2; dst = wb + 3145728; Kd = 2048; Nd = 512;  break;
    }
    const int k0 = blockIdx.x * 64, n0 = blockIdx.y * 64;
    if (k0 >= Kd || n0 >= Nd) return;
    const bool f32 = (dflag[0] == 0);
    __shared__ ushort_t T[64][65];
    const int tid = threadIdx.x;
#pragma unroll
    for (int i = 0; i < 16; ++i) {
        int j = i * 256 + tid;
        int r = j >> 6, c = j & 63;
        float v = f32 ? ((const float*)src)[(size_t)(k0 + r) * Nd + n0 + c]
                      : bf2f(((const ushort_t*)src)[(size_t)(k0 + r) * Nd + n0 + c]);
        T[r][c] = f2bf(v);
    }
    __syncthreads();
#pragma unroll
    for (int i = 0; i < 16; ++i) {
        int j = i * 256 + tid;
        int n = j >> 6, k = j & 63;
        dst[(size_t)(n0 + n) * Kd + k0 + k] = T[k][n];
    }
}

// activations tgt/mem -> bf16 (grid.x=2048, grid.y=2)
__global__ __launch_bounds__(256) void conv_act(
    const void* __restrict__ t, const void* __restrict__ m,
    ushort_t* __restrict__ td, ushort_t* __restrict__ md,
    const int* __restrict__ dflag)
{
    const bool f32 = (dflag[0] == 0);
    const void* src = blockIdx.y ? m : t;
    ushort_t* dst = blockIdx.y ? md : td;
    const int i = (blockIdx.x * 256 + threadIdx.x) * 4;
    if (f32) {
        float4 v = *(const float4*)((const float*)src + i);
        ushort_t o[4] = { f2bf(v.x), f2bf(v.y), f2bf(v.z), f2bf(v.w) };
        *(uint2*)(dst + i) = *(const uint2*)o;
    } else {
        *(uint2*)(dst + i) = *(const uint2*)((const ushort_t*)src + i);
    }
}

// all biases -> packed f32 [6656]; grid 26 x 256
__global__ __launch_bounds__(256) void prep_bias(
    const void* sbq, const void* sbk, const void* sbv, const void* sbo,
    const void* cbq, const void* cbk, const void* cbv, const void* cbo,
    const void* fb1, const void* fb2,
    float* __restrict__ dst, const int* __restrict__ dflag)
{
    const bool f32 = (dflag[0] == 0);
    const int i = blockIdx.x * 256 + threadIdx.x;
    if (i >= 6656) return;
    const void* src; int off;
    if      (i < 512)  { src = sbq; off = i; }
    else if (i < 1024) { src = sbk; off = i - 512; }
    else if (i < 1536) { src = sbv; off = i - 1024; }
    else if (i < 2048) { src = sbo; off = i - 1536; }
    else if (i < 2560) { src = cbq; off = i - 2048; }
    else if (i < 3072) { src = cbk; off = i - 2560; }
    else if (i < 3584) { src = cbv; off = i - 3072; }
    else if (i < 4096) { src = cbo; off = i - 3584; }
    else if (i < 6144) { src = fb1; off = i - 4096; }
    else               { src = fb2; off = i - 6144; }
    dst[i] = f32 ? ((const float*)src)[off] : bf2f(((const ushort_t*)src)[off]);
}

// ---------------------------------------------------------------------------
// GEMM (m97 structure): C[M][N] = act(A[M][K] @ Wt[N][K]^T + bias).
// 128x128 tile, BK=32, 4 waves x 4x4 mfma_f32_16x16x32_bf16, A and B staged
// via global_load_lds dwordx4 (2 insts each), 2-barrier K-loop.
// All operands internal bf16; bias packed f32.
// ---------------------------------------------------------------------------
template<typename OutT, bool RELU, bool ACCUM>
__global__ __launch_bounds__(256) void gemm_tn(
    const ushort_t* __restrict__ A, int lda,
    const ushort_t* __restrict__ Wt, int ldw,
    const float* __restrict__ bias,
    OutT* __restrict__ C, int ldc, int K)
{
    __shared__ ushort_t As[128][32];
    __shared__ ushort_t Bs[128][32];
    const int tid = threadIdx.x;
    const int wave = tid >> 6, lane = tid & 63;
    const int quad = lane >> 4, l16 = lane & 15;
    const int m0 = blockIdx.x * 128, n0 = blockIdx.y * 128;
    const int wm = (wave >> 1) * 64, wn = (wave & 1) * 64;

    float4v acc[4][4];
#pragma unroll
    for (int mi = 0; mi < 4; ++mi)
#pragma unroll
        for (int ni = 0; ni < 4; ++ni) {
            acc[mi][ni][0] = 0.f; acc[mi][ni][1] = 0.f;
            acc[mi][ni][2] = 0.f; acc[mi][ni][3] = 0.f;
        }

    const int lr = lane >> 2, lc = (lane & 3) * 8;
    const ushort_t* aptr = A  + (size_t)(m0 + wave * 16 + lr) * lda + lc;
    const ushort_t* bptr = Wt + (size_t)(n0 + wave * 16 + lr) * ldw + lc;
    ushort_t* asl = &As[wave * 16][0];   // wave-uniform LDS base
    ushort_t* bsl = &Bs[wave * 16][0];
    const size_t a64 = (size_t)64 * lda, b64 = (size_t)64 * ldw;

    for (int k0 = 0; k0 < K; k0 += 32) {
        gll16(aptr,       asl);
        gll16(aptr + a64, asl + 64 * 32);
        gll16(bptr,       bsl);
        gll16(bptr + b64, bsl + 64 * 32);
        aptr += 32; bptr += 32;
        __syncthreads();   // drains vmcnt (global_load_lds) before LDS reads

        short8 af[4], bfr[4];
#pragma unroll
        for (int mi = 0; mi < 4; ++mi)
            af[mi] = *(const short8*)(&As[wm + mi * 16 + l16][quad * 8]);
#pragma unroll
        for (int ni = 0; ni < 4; ++ni)
            bfr[ni] = *(const short8*)(&Bs[wn + ni * 16 + l16][quad * 8]);
#pragma unroll
        for (int mi = 0; mi < 4; ++mi)
#pragma unroll
            for (int ni = 0; ni < 4; ++ni)
                acc[mi][ni] = __builtin_amdgcn_mfma_f32_16x16x32_bf16(
                    af[mi], bfr[ni], acc[mi][ni], 0, 0, 0);
        __syncthreads();   // protect LDS from next iteration's staging
    }

#pragma unroll
    for (int ni = 0; ni < 4; ++ni) {
        const int col = n0 + wn + ni * 16 + l16;
        const float bv = ACCUM ? 0.f : bias[col];
#pragma unroll
        for (int mi = 0; mi < 4; ++mi)
#pragma unroll
            for (int r = 0; r < 4; ++r) {
                const int row = m0 + wm + mi * 16 + quad * 4 + r;
                float v = acc[mi][ni][r] + bv;
                if (ACCUM) v += ((const float*)C)[(size_t)row * ldc + col];
                if (RELU) v = fmaxf(v, 0.f);
                store_out(&C[(size_t)row * ldc + col], v);
            }
    }
}

// ---------------------------------------------------------------------------
// Flash attention (MFMA) over packed qkv [4096][1536]: Q cols 0..511,
// K cols 512..1023, V cols 1024..1535 (head h at +h*64). O written in-place
// over Q (block-disjoint 64-row x 64-col tiles). Same structure as round 5.
// ---------------------------------------------------------------------------
__global__ __launch_bounds__(256) void attn_mfma(ushort_t* __restrict__ QKV)
{
    const int S = 1536;
    __shared__ ushort_t Qs[64][72];
    __shared__ ushort_t Ks[64][72];
    __shared__ ushort_t Vt[64][72];
    __shared__ ushort_t Ps[4][16][72];

    const int tid  = threadIdx.x;
    const int wave = tid >> 6, lane = tid & 63;
    const int quad = lane >> 4, l16 = lane & 15;
    const int qt = blockIdx.x, bh = blockIdx.y;
    const int b = bh >> 3, h = bh & 7;
    const size_t rowQ = (size_t)b * 1024 + qt * 64;
    const size_t kv0  = (size_t)b * 1024;

    {
        const int r = tid >> 2, c = (tid & 3) * 16;
        const ushort_t* src = QKV + (rowQ + r) * S + h * 64 + c;
        *(uint4*)(&Qs[r][c])     = *(const uint4*)(src);
        *(uint4*)(&Qs[r][c + 8]) = *(const uint4*)(src + 8);
    }
    __syncthreads();
    short8 qf[2];
    qf[0] = *(const short8*)(&Qs[wave * 16 + l16][quad * 8]);
    qf[1] = *(const short8*)(&Qs[wave * 16 + l16][32 + quad * 8]);

    const float CEXP = 0.125f * 1.44269504f;
    float m_i[4], l_i[4];
    float4v oacc[4];
#pragma unroll
    for (int r = 0; r < 4; ++r) { m_i[r] = -1e30f; l_i[r] = 0.f; }
#pragma unroll
    for (int n = 0; n < 4; ++n) { oacc[n][0]=0.f; oacc[n][1]=0.f; oacc[n][2]=0.f; oacc[n][3]=0.f; }

    for (int s0 = 0; s0 < 1024; s0 += 64) {
        __syncthreads();
        {
            const int r = tid >> 2, c = (tid & 3) * 16;
            const ushort_t* ksrc = QKV + (kv0 + s0 + r) * S + 512 + h * 64 + c;
            *(uint4*)(&Ks[r][c])     = *(const uint4*)(ksrc);
            *(uint4*)(&Ks[r][c + 8]) = *(const uint4*)(ksrc + 8);
            const ushort_t* vsrc = QKV + (kv0 + s0 + r) * S + 1024 + h * 64 + c;
            ushort_t ve[16];
            *(uint4*)(&ve[0]) = *(const uint4*)(vsrc);
            *(uint4*)(&ve[8]) = *(const uint4*)(vsrc + 8);
#pragma unroll
            for (int j = 0; j < 16; ++j) {
                const int d = c + j;
                const int cc = ((r >> 3) ^ (d >> 4)) & 7;
                Vt[d][cc * 8 + (r & 7)] = ve[j];
            }
        }
        __syncthreads();

        float4v sc[4];
#pragma unroll
        for (int sb = 0; sb < 4; ++sb) {
            float4v z; z[0]=0.f; z[1]=0.f; z[2]=0.f; z[3]=0.f;
            short8 kf0 = *(const short8*)(&Ks[sb * 16 + l16][quad * 8]);
            short8 kf1 = *(const short8*)(&Ks[sb * 16 + l16][32 + quad * 8]);
            z = __builtin_amdgcn_mfma_f32_16x16x32_bf16(qf[0], kf0, z, 0, 0, 0);
            z = __builtin_amdgcn_mfma_f32_16x16x32_bf16(qf[1], kf1, z, 0, 0, 0);
            sc[sb] = z;
        }

        float mt[4], al[4], rs[4];
#pragma unroll
        for (int r = 0; r < 4; ++r)
            mt[r] = fmaxf(fmaxf(sc[0][r], sc[1][r]), fmaxf(sc[2][r], sc[3][r]));
#pragma unroll
        for (int msk = 1; msk < 16; msk <<= 1)
#pragma unroll
            for (int r = 0; r < 4; ++r) mt[r] = fmaxf(mt[r], __shfl_xor(mt[r], msk));
#pragma unroll
        for (int r = 0; r < 4; ++r) {
            float mn = fmaxf(m_i[r], mt[r]);
            al[r] = exp2f((m_i[r] - mn) * CEXP);
            m_i[r] = mn; rs[r] = 0.f;
        }
#pragma unroll
        for (int sb = 0; sb < 4; ++sb)
#pragma unroll
            for (int r = 0; r < 4; ++r) {
                float p = exp2f((sc[sb][r] - m_i[r]) * CEXP);
                rs[r] += p;
                Ps[wave][quad * 4 + r][sb * 16 + l16] = f2bf(p);
            }
#pragma unroll
        for (int msk = 1; msk < 16; msk <<= 1)
#pragma unroll
            for (int r = 0; r < 4; ++r) rs[r] += __shfl_xor(rs[r], msk);
#pragma unroll
        for (int r = 0; r < 4; ++r) l_i[r] = l_i[r] * al[r] + rs[r];
#pragma unroll
        for (int n = 0; n < 4; ++n)
#pragma unroll
            for (int r = 0; r < 4; ++r) oacc[n][r] *= al[r];

        short8 pf[2];
        pf[0] = *(const short8*)(&Ps[wave][l16][quad * 8]);
        pf[1] = *(const short8*)(&Ps[wave][l16][32 + quad * 8]);
#pragma unroll
        for (int n = 0; n < 4; ++n) {
#pragma unroll
            for (int kc = 0; kc < 2; ++kc) {
                const int cc = ((kc * 4 + quad) ^ n) & 7;
                short8 vf = *(const short8*)(&Vt[n * 16 + l16][cc * 8]);
                oacc[n] = __builtin_amdgcn_mfma_f32_16x16x32_bf16(pf[kc], vf, oacc[n], 0, 0, 0);
            }
        }
    }

    float inv[4];
#pragma unroll
    for (int r = 0; r < 4; ++r) inv[r] = 1.f / l_i[r];
#pragma unroll
    for (int n = 0; n < 4; ++n)
#pragma unroll
        for (int r = 0; r < 4; ++r) {
            const size_t row = rowQ + wave * 16 + quad * 4 + r;
            QKV[row * S + h * 64 + n * 16 + l16] = f2bf(oacc[n][r] * inv[r]);
        }
}

// ---------------------------------------------------------------------------
// LayerNorm over E=512 (unchanged from round 5, passed).
// ---------------------------------------------------------------------------
template<bool RES_EXT, bool DELTA_F32, bool OUT_FLAG>
__global__ __launch_bounds__(256) void ln_kernel(
    const void* __restrict__ res, const void* __restrict__ delta,
    const void* __restrict__ g, const void* __restrict__ be,
    void* __restrict__ out, const int* __restrict__ dflag)
{
    const int E = 512;
    const bool extf32 = (dflag[0] == 0);
    const int row = blockIdx.x, tid = threadIdx.x;
    const size_t base = (size_t)row * E;
    const int i0 = tid, i1 = tid + 256;

    float r0, r1;
    if (RES_EXT && extf32) {
        r0 = ((const float*)res)[base + i0];
        r1 = ((const float*)res)[base + i1];
    } else {
        r0 = bf2f(((const ushort_t*)res)[base + i0]);
        r1 = bf2f(((const ushort_t*)res)[base + i1]);
    }
    float d0v, d1v;
    if (DELTA_F32) {
        d0v = ((const float*)delta)[base + i0];
        d1v = ((const float*)delta)[base + i1];
    } else {
        d0v = bf2f(((const ushort_t*)delta)[base + i0]);
        d1v = bf2f(((const ushort_t*)delta)[base + i1]);
    }
    float x0 = r0 + d0v, x1 = r1 + d1v;

    __shared__ float red[256];
    red[tid] = x0 + x1; __syncthreads();
    for (int off = 128; off > 0; off >>= 1) {
        if (tid < off) red[tid] += red[tid + off];
        __syncthreads();
    }
    float mean = red[0] * (1.0f / 512.0f); __syncthreads();
    float dd0 = x0 - mean, dd1 = x1 - mean;
    red[tid] = dd0 * dd0 + dd1 * dd1; __syncthreads();
    for (int off = 128; off > 0; off >>= 1) {
        if (tid < off) red[tid] += red[tid + off];
        __syncthreads();
    }
    float rstd = rsqrtf(red[0] * (1.0f / 512.0f) + 1e-5f);

    float g0, g1v, b0, b1;
    if (extf32) {
        g0 = ((const float*)g)[i0];  g1v = ((const float*)g)[i1];
        b0 = ((const float*)be)[i0]; b1  = ((const float*)be)[i1];
    } else {
        g0 = bf2f(((const ushort_t*)g)[i0]);  g1v = bf2f(((const ushort_t*)g)[i1]);
        b0 = bf2f(((const ushort_t*)be)[i0]); b1  = bf2f(((const ushort_t*)be)[i1]);
    }
    float y0 = dd0 * rstd * g0 + b0;
    float y1 = dd1 * rstd * g1v + b1;
    if (OUT_FLAG && extf32) {
        ((float*)out)[base + i0] = y0; ((float*)out)[base + i1] = y1;
    } else {
        ((ushort_t*)out)[base + i0] = f2bf(y0);
        ((ushort_t*)out)[base + i1] = f2bf(y1);
    }
}

// ---------------------------------------------------------------------------
// Workspace (~36.3 MiB):
//   [ 0 ..12M) qkv bf16 [4096][1536]   (FFN: [0..8M) reused as `of` f32)
//   [12M..16M) po  bf16 [4096][512]
//   [16M..20M) xb  bf16 [4096][512]
//   [20M..24M) tb  bf16 (tgt)   } clobbered by hb [4096][1024] during FFN
//   [24M..28M) mb  bf16 (mem)   }
//   [28M..36M) wb  bf16 transposed weights (layout in wtrans_all)
//   [36M..+26K) pb f32 packed biases
//   [36M+256K] dflag
// ---------------------------------------------------------------------------

extern "C" void kernel_launch(void* const* d_in, const int* in_sizes, int n_in,
                              void* d_out, int out_size, void* d_ws, size_t ws_size,
                              hipStream_t stream) {
    const void* tgt = d_in[0];
    const void* mem = d_in[1];
    const void* sWq = d_in[2];  const void* sWk = d_in[3];
    const void* sWv = d_in[4];  const void* sWo = d_in[5];
    const void* cWq = d_in[6];  const void* cWk = d_in[7];
    const void* cWv = d_in[8];  const void* cWo = d_in[9];
    const void* sbq = d_in[10]; const void* sbk = d_in[11];
    const void* sbv = d_in[12]; const void* sbo = d_in[13];
    const void* cbq = d_in[14]; const void* cbk = d_in[15];
    const void* cbv = d_in[16]; const void* cbo = d_in[17];
    const void* fW1 = d_in[18]; const void* fb1 = d_in[19];
    const void* fW2 = d_in[20]; const void* fb2 = d_in[21];
    const void* g1  = d_in[22]; const void* g2  = d_in[23];
    const void* g3  = d_in[24];
    const void* be1 = d_in[25]; const void* be2 = d_in[26];
    const void* be3 = d_in[27];

    char* ws = (char*)d_ws;
    const size_t MB = 1048576;
    ushort_t* qkv = (ushort_t*)(ws + 0 * MB);
    float*    of  = (float*)   (ws + 0 * MB);
    ushort_t* po  = (ushort_t*)(ws + 12 * MB);
    ushort_t* xb  = (ushort_t*)(ws + 16 * MB);
    ushort_t* tb  = (ushort_t*)(ws + 20 * MB);
    ushort_t* mb  = (ushort_t*)(ws + 24 * MB);
    ushort_t* hb  = (ushort_t*)(ws + 20 * MB);   // FFN hidden chunk [4096][1024]
    ushort_t* wb  = (ushort_t*)(ws + 28 * MB);
    float*    pb  = (float*)   (ws + 36 * MB);
    int*   dflag  = (int*)     (ws + 36 * MB + 262144);

    const ushort_t* sWqkv_t = wb + 0;
    const ushort_t* sWo_t   = wb + 786432;
    const ushort_t* cWq_t   = wb + 1048576;
    const ushort_t* cWkv_t  = wb + 1310720;
    const ushort_t* cWo_t   = wb + 1835008;
    const ushort_t* fW1_t   = wb + 2097152;
    const ushort_t* fW2_t   = wb + 3145728;

    dim3 blk(256);

    // ---- prep: dtype flag, weights->bf16 [N][K], acts->bf16, biases->f32 ----
    detect_dtype<<<dim3(1), blk, 0, stream>>>((const ushort_t*)tgt, dflag);
    wtrans_all<<<dim3(32, 32, 10), blk, 0, stream>>>(sWq, sWk, sWv, sWo, cWq, cWk, cWv, cWo, fW1, fW2, wb, dflag);
    conv_act<<<dim3(2048, 2), blk, 0, stream>>>(tgt, mem, tb, mb, dflag);
    prep_bias<<<dim3(26), blk, 0, stream>>>(sbq, sbk, sbv, sbo, cbq, cbk, cbv, cbo, fb1, fb2, pb, dflag);

    dim3 gattn(16, 32);

    // ---- self-attention ----
    gemm_tn<ushort_t, false, false><<<dim3(32, 12), blk, 0, stream>>>(tb, 512, sWqkv_t, 512, pb + 0, qkv, 1536, 512);
    attn_mfma<<<gattn, blk, 0, stream>>>(qkv);
    gemm_tn<ushort_t, false, false><<<dim3(32, 4), blk, 0, stream>>>(qkv, 1536, sWo_t, 512, pb + 1536, po, 512, 512);
    ln_kernel<true, false, false><<<dim3(4096), blk, 0, stream>>>(tgt, po, g1, be1, xb, dflag);

    // ---- cross-attention ----
    gemm_tn<ushort_t, false, false><<<dim3(32, 4), blk, 0, stream>>>(xb, 512, cWq_t, 512, pb + 2048, qkv, 1536, 512);
    gemm_tn<ushort_t, false, false><<<dim3(32, 8), blk, 0, stream>>>(mb, 512, cWkv_t, 512, pb + 2560, qkv + 512, 1536, 512);
    attn_mfma<<<gattn, blk, 0, stream>>>(qkv);
    gemm_tn<ushort_t, false, false><<<dim3(32, 4), blk, 0, stream>>>(qkv, 1536, cWo_t, 512, pb + 3584, po, 512, 512);
    ln_kernel<false, false, false><<<dim3(4096), blk, 0, stream>>>(xb, po, g2, be2, xb, dflag);

    // ---- FFN: 2 N-chunks of fW1 / K-chunks of fW2, f32 accum in `of` ----
    gemm_tn<ushort_t, true, false><<<dim3(32, 8), blk, 0, stream>>>(xb, 512, fW1_t, 512, pb + 4096, hb, 1024, 512);
    gemm_tn<float, false, false><<<dim3(32, 4), blk, 0, stream>>>(hb, 1024, fW2_t, 2048, pb + 6144, of, 512, 1024);
    gemm_tn<ushort_t, true, false><<<dim3(32, 8), blk, 0, stream>>>(xb, 512, fW1_t + 1024 * 512, 512, pb + 5120, hb, 1024, 512);
    gemm_tn<float, false, true><<<dim3(32, 4), blk, 0, stream>>>(hb, 1024, fW2_t + 1024, 2048, nullptr, of, 512, 1024);
    ln_kernel<false, true, true><<<dim3(4096), blk, 0, stream>>>(xb, of, g3, be3, d_out, dflag);
}

// Round 7
// 398.218 us; speedup vs baseline: 5.8147x; 1.0565x over previous
//
#include <hip/hip_runtime.h>

typedef unsigned short ushort_t;
typedef short short8 __attribute__((ext_vector_type(8)));
typedef float float4v __attribute__((ext_vector_type(4)));

__device__ __forceinline__ float bf2f(ushort_t u) {
    union { unsigned int i; float f; } x; x.i = ((unsigned int)u) << 16; return x.f;
}
__device__ __forceinline__ ushort_t f2bf(float f) {
    unsigned int u = __float_as_uint(f);
    unsigned int r = (u + 0x7FFFu + ((u >> 16) & 1u)) >> 16;
    return (ushort_t)r;
}
__device__ __forceinline__ void store_out(float* p, float v) { *p = v; }
__device__ __forceinline__ void store_out(ushort_t* p, float v) { *p = f2bf(v); }

// async global->LDS 16B/lane; lds ptr must be wave-uniform base (lane*16 auto)
__device__ __forceinline__ void gll16(const ushort_t* g, ushort_t* l) {
    __builtin_amdgcn_global_load_lds(
        (const __attribute__((address_space(1))) void*)g,
        (__attribute__((address_space(3))) void*)l, 16, 0, 0);
}

// ---------------------------------------------------------------------------
// Input-dtype detection. flag=1 -> inputs bf16; flag=0 -> inputs f32.
// ---------------------------------------------------------------------------
__global__ void detect_dtype(const ushort_t* __restrict__ tgt, int* __restrict__ flag) {
    __shared__ int red[256];
    const int tid = threadIdx.x;
    int p = 0;
    for (int i = tid; i < 512; i += 256) {
        ushort_t u = tgt[i];
        int e = (u >> 7) & 0xFF;
        if (u == 0 || (e >= 100 && e <= 140)) ++p;
    }
    red[tid] = p; __syncthreads();
    for (int off = 128; off > 0; off >>= 1) {
        if (tid < off) red[tid] += red[tid + off];
        __syncthreads();
    }
    if (tid == 0) flag[0] = (red[0] >= 480) ? 1 : 0;
}

// ---------------------------------------------------------------------------
// Weight prep: src[K][N] (ext dtype) -> dst[N][K] bf16, via 64x64 LDS tile.
// ---------------------------------------------------------------------------
__global__ __launch_bounds__(256) void wtrans_all(
    const void* sWq, const void* sWk, const void* sWv, const void* sWo,
    const void* cWq, const void* cWk, const void* cWv, const void* cWo,
    const void* fW1, const void* fW2,
    ushort_t* __restrict__ wb, const int* __restrict__ dflag)
{
    const void* src; ushort_t* dst; int Kd, Nd;
    switch (blockIdx.z) {
        case 0: src = sWq; dst = wb + 0;       Kd = 512;  Nd = 512;  break;
        case 1: src = sWk; dst = wb + 262144;  Kd = 512;  Nd = 512;  break;
        case 2: src = sWv; dst = wb + 524288;  Kd = 512;  Nd = 512;  break;
        case 3: src = sWo; dst = wb + 786432;  Kd = 512;  Nd = 512;  break;
        case 4: src = cWq; dst = wb + 1048576; Kd = 512;  Nd = 512;  break;
        case 5: src = cWk; dst = wb + 1310720; Kd = 512;  Nd = 512;  break;
        case 6: src = cWv; dst = wb + 1572864; Kd = 512;  Nd = 512;  break;
        case 7: src = cWo; dst = wb + 1835008; Kd = 512;  Nd = 512;  break;
        case 8: src = fW1; dst = wb + 2097152; Kd = 512;  Nd = 2048; break;
        default:src = fW2; dst = wb + 3145728; Kd = 2048; Nd = 512;  break;
    }
    const int k0 = blockIdx.x * 64, n0 = blockIdx.y * 64;
    if (k0 >= Kd || n0 >= Nd) return;
    const bool f32 = (dflag[0] == 0);
    __shared__ ushort_t T[64][65];
    const int tid = threadIdx.x;
#pragma unroll
    for (int i = 0; i < 16; ++i) {
        int j = i * 256 + tid;
        int r = j >> 6, c = j & 63;
        float v = f32 ? ((const float*)src)[(size_t)(k0 + r) * Nd + n0 + c]
                      : bf2f(((const ushort_t*)src)[(size_t)(k0 + r) * Nd + n0 + c]);
        T[r][c] = f2bf(v);
    }
    __syncthreads();
#pragma unroll
    for (int i = 0; i < 16; ++i) {
        int j = i * 256 + tid;
        int n = j >> 6, k = j & 63;
        dst[(size_t)(n0 + n) * Kd + k0 + k] = T[k][n];
    }
}

// activations tgt/mem -> bf16 (grid.x=2048, grid.y=2)
__global__ __launch_bounds__(256) void conv_act(
    const void* __restrict__ t, const void* __restrict__ m,
    ushort_t* __restrict__ td, ushort_t* __restrict__ md,
    const int* __restrict__ dflag)
{
    const bool f32 = (dflag[0] == 0);
    const void* src = blockIdx.y ? m : t;
    ushort_t* dst = blockIdx.y ? md : td;
    const int i = (blockIdx.x * 256 + threadIdx.x) * 4;
    if (f32) {
        float4 v = *(const float4*)((const float*)src + i);
        ushort_t o[4] = { f2bf(v.x), f2bf(v.y), f2bf(v.z), f2bf(v.w) };
        *(uint2*)(dst + i) = *(const uint2*)o;
    } else {
        *(uint2*)(dst + i) = *(const uint2*)((const ushort_t*)src + i);
    }
}

// all biases -> packed f32 [6656]; grid 26 x 256
__global__ __launch_bounds__(256) void prep_bias(
    const void* sbq, const void* sbk, const void* sbv, const void* sbo,
    const void* cbq, const void* cbk, const void* cbv, const void* cbo,
    const void* fb1, const void* fb2,
    float* __restrict__ dst, const int* __restrict__ dflag)
{
    const bool f32 = (dflag[0] == 0);
    const int i = blockIdx.x * 256 + threadIdx.x;
    if (i >= 6656) return;
    const void* src; int off;
    if      (i < 512)  { src = sbq; off = i; }
    else if (i < 1024) { src = sbk; off = i - 512; }
    else if (i < 1536) { src = sbv; off = i - 1024; }
    else if (i < 2048) { src = sbo; off = i - 1536; }
    else if (i < 2560) { src = cbq; off = i - 2048; }
    else if (i < 3072) { src = cbk; off = i - 2560; }
    else if (i < 3584) { src = cbv; off = i - 3072; }
    else if (i < 4096) { src = cbo; off = i - 3584; }
    else if (i < 6144) { src = fb1; off = i - 4096; }
    else               { src = fb2; off = i - 6144; }
    dst[i] = f32 ? ((const float*)src)[off] : bf2f(((const ushort_t*)src)[off]);
}

// ---------------------------------------------------------------------------
// GEMM: C[M][N] = act(A[M][K] @ Wt[N][K]^T + bias). 128x128 tile, BK=64,
// 4 waves x 4x4 mfma_f32_16x16x32_bf16 x 2 k-steps (32 MFMAs per barrier
// pair). Staging via global_load_lds dwordx4 with a per-lane XOR column
// swizzle: LDS[r][chunk] holds global k-chunk (chunk ^ (r&7)), so staging
// stays coalesced (permutation inside each 128B segment) AND b128 frag
// reads touch 8 distinct 4-bank groups (2-way = free) instead of the
// 16-way conflict a linear BK=64 layout would have. Padding is impossible
// with global_load_lds (wave-uniform base), hence the swizzle.
// ---------------------------------------------------------------------------
template<typename OutT, bool RELU, bool ACCUM>
__global__ __launch_bounds__(256) void gemm_tn(
    const ushort_t* __restrict__ A, int lda,
    const ushort_t* __restrict__ Wt, int ldw,
    const float* __restrict__ bias,
    OutT* __restrict__ C, int ldc, int K)
{
    __shared__ ushort_t As[128][64];
    __shared__ ushort_t Bs[128][64];
    const int tid = threadIdx.x;
    const int wave = tid >> 6, lane = tid & 63;
    const int quad = lane >> 4, l16 = lane & 15;
    const int m0 = blockIdx.x * 128, n0 = blockIdx.y * 128;
    const int wm = (wave >> 1) * 64, wn = (wave & 1) * 64;

    float4v acc[4][4];
#pragma unroll
    for (int mi = 0; mi < 4; ++mi)
#pragma unroll
        for (int ni = 0; ni < 4; ++ni) {
            acc[mi][ni][0] = 0.f; acc[mi][ni][1] = 0.f;
            acc[mi][ni][2] = 0.f; acc[mi][ni][3] = 0.f;
        }

    const int lr = lane >> 3;                      // 0..7 row within 8-row slab
    const int lcsw = ((lane & 7) ^ lr) * 8;        // swizzled k-chunk source
    const ushort_t* aptr = A  + (size_t)(m0 + wave * 8 + lr) * lda + lcsw;
    const ushort_t* bptr = Wt + (size_t)(n0 + wave * 8 + lr) * ldw + lcsw;
    ushort_t* asl = &As[wave * 8][0];              // wave-uniform LDS base
    ushort_t* bsl = &Bs[wave * 8][0];
    const int xsw = (l16 & 7);                     // frag-read XOR key (= r&7)

    for (int k0 = 0; k0 < K; k0 += 64) {
#pragma unroll
        for (int j = 0; j < 4; ++j) {
            gll16(aptr + (size_t)(j * 32) * lda, asl + j * 32 * 64);
            gll16(bptr + (size_t)(j * 32) * ldw, bsl + j * 32 * 64);
        }
        aptr += 64; bptr += 64;
        __syncthreads();   // drains vmcnt (global_load_lds) before LDS reads

#pragma unroll
        for (int ks = 0; ks < 2; ++ks) {
            const int ca = ((quad + ks * 4) ^ xsw) * 8;
            short8 af[4], bfr[4];
#pragma unroll
            for (int mi = 0; mi < 4; ++mi)
                af[mi] = *(const short8*)(&As[wm + mi * 16 + l16][ca]);
#pragma unroll
            for (int ni = 0; ni < 4; ++ni)
                bfr[ni] = *(const short8*)(&Bs[wn + ni * 16 + l16][ca]);
#pragma unroll
            for (int mi = 0; mi < 4; ++mi)
#pragma unroll
                for (int ni = 0; ni < 4; ++ni)
                    acc[mi][ni] = __builtin_amdgcn_mfma_f32_16x16x32_bf16(
                        af[mi], bfr[ni], acc[mi][ni], 0, 0, 0);
        }
        __syncthreads();   // protect LDS from next iteration's staging
    }

#pragma unroll
    for (int ni = 0; ni < 4; ++ni) {
        const int col = n0 + wn + ni * 16 + l16;
        const float bv = ACCUM ? 0.f : bias[col];
#pragma unroll
        for (int mi = 0; mi < 4; ++mi)
#pragma unroll
            for (int r = 0; r < 4; ++r) {
                const int row = m0 + wm + mi * 16 + quad * 4 + r;
                float v = acc[mi][ni][r] + bv;
                if (ACCUM) v += ((const float*)C)[(size_t)row * ldc + col];
                if (RELU) v = fmaxf(v, 0.f);
                store_out(&C[(size_t)row * ldc + col], v);
            }
    }
}

// ---------------------------------------------------------------------------
// Flash attention (MFMA) over packed qkv [4096][1536]: Q cols 0..511,
// K cols 512..1023, V cols 1024..1535 (head h at +h*64). O written in-place
// over Q (block-disjoint 64-row x 64-col tiles). Unchanged from round 6.
// ---------------------------------------------------------------------------
__global__ __launch_bounds__(256) void attn_mfma(ushort_t* __restrict__ QKV)
{
    const int S = 1536;
    __shared__ ushort_t Qs[64][72];
    __shared__ ushort_t Ks[64][72];
    __shared__ ushort_t Vt[64][72];
    __shared__ ushort_t Ps[4][16][72];

    const int tid  = threadIdx.x;
    const int wave = tid >> 6, lane = tid & 63;
    const int quad = lane >> 4, l16 = lane & 15;
    const int qt = blockIdx.x, bh = blockIdx.y;
    const int b = bh >> 3, h = bh & 7;
    const size_t rowQ = (size_t)b * 1024 + qt * 64;
    const size_t kv0  = (size_t)b * 1024;

    {
        const int r = tid >> 2, c = (tid & 3) * 16;
        const ushort_t* src = QKV + (rowQ + r) * S + h * 64 + c;
        *(uint4*)(&Qs[r][c])     = *(const uint4*)(src);
        *(uint4*)(&Qs[r][c + 8]) = *(const uint4*)(src + 8);
    }
    __syncthreads();
    short8 qf[2];
    qf[0] = *(const short8*)(&Qs[wave * 16 + l16][quad * 8]);
    qf[1] = *(const short8*)(&Qs[wave * 16 + l16][32 + quad * 8]);

    const float CEXP = 0.125f * 1.44269504f;
    float m_i[4], l_i[4];
    float4v oacc[4];
#pragma unroll
    for (int r = 0; r < 4; ++r) { m_i[r] = -1e30f; l_i[r] = 0.f; }
#pragma unroll
    for (int n = 0; n < 4; ++n) { oacc[n][0]=0.f; oacc[n][1]=0.f; oacc[n][2]=0.f; oacc[n][3]=0.f; }

    for (int s0 = 0; s0 < 1024; s0 += 64) {
        __syncthreads();
        {
            const int r = tid >> 2, c = (tid & 3) * 16;
            const ushort_t* ksrc = QKV + (kv0 + s0 + r) * S + 512 + h * 64 + c;
            *(uint4*)(&Ks[r][c])     = *(const uint4*)(ksrc);
            *(uint4*)(&Ks[r][c + 8]) = *(const uint4*)(ksrc + 8);
            const ushort_t* vsrc = QKV + (kv0 + s0 + r) * S + 1024 + h * 64 + c;
            ushort_t ve[16];
            *(uint4*)(&ve[0]) = *(const uint4*)(vsrc);
            *(uint4*)(&ve[8]) = *(const uint4*)(vsrc + 8);
#pragma unroll
            for (int j = 0; j < 16; ++j) {
                const int d = c + j;
                const int cc = ((r >> 3) ^ (d >> 4)) & 7;
                Vt[d][cc * 8 + (r & 7)] = ve[j];
            }
        }
        __syncthreads();

        float4v sc[4];
#pragma unroll
        for (int sb = 0; sb < 4; ++sb) {
            float4v z; z[0]=0.f; z[1]=0.f; z[2]=0.f; z[3]=0.f;
            short8 kf0 = *(const short8*)(&Ks[sb * 16 + l16][quad * 8]);
            short8 kf1 = *(const short8*)(&Ks[sb * 16 + l16][32 + quad * 8]);
            z = __builtin_amdgcn_mfma_f32_16x16x32_bf16(qf[0], kf0, z, 0, 0, 0);
            z = __builtin_amdgcn_mfma_f32_16x16x32_bf16(qf[1], kf1, z, 0, 0, 0);
            sc[sb] = z;
        }

        float mt[4], al[4], rs[4];
#pragma unroll
        for (int r = 0; r < 4; ++r)
            mt[r] = fmaxf(fmaxf(sc[0][r], sc[1][r]), fmaxf(sc[2][r], sc[3][r]));
#pragma unroll
        for (int msk = 1; msk < 16; msk <<= 1)
#pragma unroll
            for (int r = 0; r < 4; ++r) mt[r] = fmaxf(mt[r], __shfl_xor(mt[r], msk));
#pragma unroll
        for (int r = 0; r < 4; ++r) {
            float mn = fmaxf(m_i[r], mt[r]);
            al[r] = exp2f((m_i[r] - mn) * CEXP);
            m_i[r] = mn; rs[r] = 0.f;
        }
#pragma unroll
        for (int sb = 0; sb < 4; ++sb)
#pragma unroll
            for (int r = 0; r < 4; ++r) {
                float p = exp2f((sc[sb][r] - m_i[r]) * CEXP);
                rs[r] += p;
                Ps[wave][quad * 4 + r][sb * 16 + l16] = f2bf(p);
            }
#pragma unroll
        for (int msk = 1; msk < 16; msk <<= 1)
#pragma unroll
            for (int r = 0; r < 4; ++r) rs[r] += __shfl_xor(rs[r], msk);
#pragma unroll
        for (int r = 0; r < 4; ++r) l_i[r] = l_i[r] * al[r] + rs[r];
#pragma unroll
        for (int n = 0; n < 4; ++n)
#pragma unroll
            for (int r = 0; r < 4; ++r) oacc[n][r] *= al[r];

        short8 pf[2];
        pf[0] = *(const short8*)(&Ps[wave][l16][quad * 8]);
        pf[1] = *(const short8*)(&Ps[wave][l16][32 + quad * 8]);
#pragma unroll
        for (int n = 0; n < 4; ++n) {
#pragma unroll
            for (int kc = 0; kc < 2; ++kc) {
                const int cc = ((kc * 4 + quad) ^ n) & 7;
                short8 vf = *(const short8*)(&Vt[n * 16 + l16][cc * 8]);
                oacc[n] = __builtin_amdgcn_mfma_f32_16x16x32_bf16(pf[kc], vf, oacc[n], 0, 0, 0);
            }
        }
    }

    float inv[4];
#pragma unroll
    for (int r = 0; r < 4; ++r) inv[r] = 1.f / l_i[r];
#pragma unroll
    for (int n = 0; n < 4; ++n)
#pragma unroll
        for (int r = 0; r < 4; ++r) {
            const size_t row = rowQ + wave * 16 + quad * 4 + r;
            QKV[row * S + h * 64 + n * 16 + l16] = f2bf(oacc[n][r] * inv[r]);
        }
}

// ---------------------------------------------------------------------------
// LayerNorm over E=512 (unchanged, passed).
// ---------------------------------------------------------------------------
template<bool RES_EXT, bool DELTA_F32, bool OUT_FLAG>
__global__ __launch_bounds__(256) void ln_kernel(
    const void* __restrict__ res, const void* __restrict__ delta,
    const void* __restrict__ g, const void* __restrict__ be,
    void* __restrict__ out, const int* __restrict__ dflag)
{
    const int E = 512;
    const bool extf32 = (dflag[0] == 0);
    const int row = blockIdx.x, tid = threadIdx.x;
    const size_t base = (size_t)row * E;
    const int i0 = tid, i1 = tid + 256;

    float r0, r1;
    if (RES_EXT && extf32) {
        r0 = ((const float*)res)[base + i0];
        r1 = ((const float*)res)[base + i1];
    } else {
        r0 = bf2f(((const ushort_t*)res)[base + i0]);
        r1 = bf2f(((const ushort_t*)res)[base + i1]);
    }
    float d0v, d1v;
    if (DELTA_F32) {
        d0v = ((const float*)delta)[base + i0];
        d1v = ((const float*)delta)[base + i1];
    } else {
        d0v = bf2f(((const ushort_t*)delta)[base + i0]);
        d1v = bf2f(((const ushort_t*)delta)[base + i1]);
    }
    float x0 = r0 + d0v, x1 = r1 + d1v;

    __shared__ float red[256];
    red[tid] = x0 + x1; __syncthreads();
    for (int off = 128; off > 0; off >>= 1) {
        if (tid < off) red[tid] += red[tid + off];
        __syncthreads();
    }
    float mean = red[0] * (1.0f / 512.0f); __syncthreads();
    float dd0 = x0 - mean, dd1 = x1 - mean;
    red[tid] = dd0 * dd0 + dd1 * dd1; __syncthreads();
    for (int off = 128; off > 0; off >>= 1) {
        if (tid < off) red[tid] += red[tid + off];
        __syncthreads();
    }
    float rstd = rsqrtf(red[0] * (1.0f / 512.0f) + 1e-5f);

    float g0, g1v, b0, b1;
    if (extf32) {
        g0 = ((const float*)g)[i0];  g1v = ((const float*)g)[i1];
        b0 = ((const float*)be)[i0]; b1  = ((const float*)be)[i1];
    } else {
        g0 = bf2f(((const ushort_t*)g)[i0]);  g1v = bf2f(((const ushort_t*)g)[i1]);
        b0 = bf2f(((const ushort_t*)be)[i0]); b1  = bf2f(((const ushort_t*)be)[i1]);
    }
    float y0 = dd0 * rstd * g0 + b0;
    float y1 = dd1 * rstd * g1v + b1;
    if (OUT_FLAG && extf32) {
        ((float*)out)[base + i0] = y0; ((float*)out)[base + i1] = y1;
    } else {
        ((ushort_t*)out)[base + i0] = f2bf(y0);
        ((ushort_t*)out)[base + i1] = f2bf(y1);
    }
}

// ---------------------------------------------------------------------------
// Workspace (~36.3 MiB):
//   [ 0 ..12M) qkv bf16 [4096][1536]   (FFN: [0..8M) reused as `of` f32)
//   [12M..16M) po  bf16 [4096][512]
//   [16M..20M) xb  bf16 [4096][512]
//   [20M..24M) tb  bf16 (tgt)   } clobbered by hb [4096][1024] during FFN
//   [24M..28M) mb  bf16 (mem)   }
//   [28M..36M) wb  bf16 transposed weights (layout in wtrans_all)
//   [36M..+26K) pb f32 packed biases
//   [36M+256K] dflag
// ---------------------------------------------------------------------------

extern "C" void kernel_launch(void* const* d_in, const int* in_sizes, int n_in,
                              void* d_out, int out_size, void* d_ws, size_t ws_size,
                              hipStream_t stream) {
    const void* tgt = d_in[0];
    const void* mem = d_in[1];
    const void* sWq = d_in[2];  const void* sWk = d_in[3];
    const void* sWv = d_in[4];  const void* sWo = d_in[5];
    const void* cWq = d_in[6];  const void* cWk = d_in[7];
    const void* cWv = d_in[8];  const void* cWo = d_in[9];
    const void* sbq = d_in[10]; const void* sbk = d_in[11];
    const void* sbv = d_in[12]; const void* sbo = d_in[13];
    const void* cbq = d_in[14]; const void* cbk = d_in[15];
    const void* cbv = d_in[16]; const void* cbo = d_in[17];
    const void* fW1 = d_in[18]; const void* fb1 = d_in[19];
    const void* fW2 = d_in[20]; const void* fb2 = d_in[21];
    const void* g1  = d_in[22]; const void* g2  = d_in[23];
    const void* g3  = d_in[24];
    const void* be1 = d_in[25]; const void* be2 = d_in[26];
    const void* be3 = d_in[27];

    char* ws = (char*)d_ws;
    const size_t MB = 1048576;
    ushort_t* qkv = (ushort_t*)(ws + 0 * MB);
    float*    of  = (float*)   (ws + 0 * MB);
    ushort_t* po  = (ushort_t*)(ws + 12 * MB);
    ushort_t* xb  = (ushort_t*)(ws + 16 * MB);
    ushort_t* tb  = (ushort_t*)(ws + 20 * MB);
    ushort_t* mb  = (ushort_t*)(ws + 24 * MB);
    ushort_t* hb  = (ushort_t*)(ws + 20 * MB);   // FFN hidden chunk [4096][1024]
    ushort_t* wb  = (ushort_t*)(ws + 28 * MB);
    float*    pb  = (float*)   (ws + 36 * MB);
    int*   dflag  = (int*)     (ws + 36 * MB + 262144);

    const ushort_t* sWqkv_t = wb + 0;
    const ushort_t* sWo_t   = wb + 786432;
    const ushort_t* cWq_t   = wb + 1048576;
    const ushort_t* cWkv_t  = wb + 1310720;
    const ushort_t* cWo_t   = wb + 1835008;
    const ushort_t* fW1_t   = wb + 2097152;
    const ushort_t* fW2_t   = wb + 3145728;

    dim3 blk(256);

    // ---- prep: dtype flag, weights->bf16 [N][K], acts->bf16, biases->f32 ----
    detect_dtype<<<dim3(1), blk, 0, stream>>>((const ushort_t*)tgt, dflag);
    wtrans_all<<<dim3(32, 32, 10), blk, 0, stream>>>(sWq, sWk, sWv, sWo, cWq, cWk, cWv, cWo, fW1, fW2, wb, dflag);
    conv_act<<<dim3(2048, 2), blk, 0, stream>>>(tgt, mem, tb, mb, dflag);
    prep_bias<<<dim3(26), blk, 0, stream>>>(sbq, sbk, sbv, sbo, cbq, cbk, cbv, cbo, fb1, fb2, pb, dflag);

    dim3 gattn(16, 32);

    // ---- self-attention ----
    gemm_tn<ushort_t, false, false><<<dim3(32, 12), blk, 0, stream>>>(tb, 512, sWqkv_t, 512, pb + 0, qkv, 1536, 512);
    attn_mfma<<<gattn, blk, 0, stream>>>(qkv);
    gemm_tn<ushort_t, false, false><<<dim3(32, 4), blk, 0, stream>>>(qkv, 1536, sWo_t, 512, pb + 1536, po, 512, 512);
    ln_kernel<true, false, false><<<dim3(4096), blk, 0, stream>>>(tgt, po, g1, be1, xb, dflag);

    // ---- cross-attention ----
    gemm_tn<ushort_t, false, false><<<dim3(32, 4), blk, 0, stream>>>(xb, 512, cWq_t, 512, pb + 2048, qkv, 1536, 512);
    gemm_tn<ushort_t, false, false><<<dim3(32, 8), blk, 0, stream>>>(mb, 512, cWkv_t, 512, pb + 2560, qkv + 512, 1536, 512);
    attn_mfma<<<gattn, blk, 0, stream>>>(qkv);
    gemm_tn<ushort_t, false, false><<<dim3(32, 4), blk, 0, stream>>>(qkv, 1536, cWo_t, 512, pb + 3584, po, 512, 512);
    ln_kernel<false, false, false><<<dim3(4096), blk, 0, stream>>>(xb, po, g2, be2, xb, dflag);

    // ---- FFN: 2 N-chunks of fW1 / K-chunks of fW2, f32 accum in `of` ----
    gemm_tn<ushort_t, true, false><<<dim3(32, 8), blk, 0, stream>>>(xb, 512, fW1_t, 512, pb + 4096, hb, 1024, 512);
    gemm_tn<float, false, false><<<dim3(32, 4), blk, 0, stream>>>(hb, 1024, fW2_t, 2048, pb + 6144, of, 512, 1024);
    gemm_tn<ushort_t, true, false><<<dim3(32, 8), blk, 0, stream>>>(xb, 512, fW1_t + 1024 * 512, 512, pb + 5120, hb, 1024, 512);
    gemm_tn<float, false, true><<<dim3(32, 4), blk, 0, stream>>>(hb, 1024, fW2_t + 1024, 2048, nullptr, of, 512, 1024);
    ln_kernel<false, true, true><<<dim3(4096), blk, 0, stream>>>(xb, of, g3, be3, d_out, dflag);
}

// Round 8
// 323.057 us; speedup vs baseline: 7.1675x; 1.2327x over previous
//
#include <hip/hip_runtime.h>

typedef unsigned short ushort_t;
typedef short short8 __attribute__((ext_vector_type(8)));
typedef float float4v __attribute__((ext_vector_type(4)));

__device__ __forceinline__ float bf2f(ushort_t u) {
    union { unsigned int i; float f; } x; x.i = ((unsigned int)u) << 16; return x.f;
}
__device__ __forceinline__ ushort_t f2bf(float f) {
    unsigned int u = __float_as_uint(f);
    unsigned int r = (u + 0x7FFFu + ((u >> 16) & 1u)) >> 16;
    return (ushort_t)r;
}
__device__ __forceinline__ void store_out(float* p, float v) { *p = v; }
__device__ __forceinline__ void store_out(ushort_t* p, float v) { *p = f2bf(v); }

// async global->LDS 16B/lane; lds ptr must be wave-uniform base (lane*16 auto)
__device__ __forceinline__ void gll16(const ushort_t* g, ushort_t* l) {
    __builtin_amdgcn_global_load_lds(
        (const __attribute__((address_space(1))) void*)g,
        (__attribute__((address_space(3))) void*)l, 16, 0, 0);
}

// ---------------------------------------------------------------------------
// Input-dtype detection. flag=1 -> inputs bf16; flag=0 -> inputs f32.
// ---------------------------------------------------------------------------
__global__ void detect_dtype(const ushort_t* __restrict__ tgt, int* __restrict__ flag) {
    __shared__ int red[256];
    const int tid = threadIdx.x;
    int p = 0;
    for (int i = tid; i < 512; i += 256) {
        ushort_t u = tgt[i];
        int e = (u >> 7) & 0xFF;
        if (u == 0 || (e >= 100 && e <= 140)) ++p;
    }
    red[tid] = p; __syncthreads();
    for (int off = 128; off > 0; off >>= 1) {
        if (tid < off) red[tid] += red[tid + off];
        __syncthreads();
    }
    if (tid == 0) flag[0] = (red[0] >= 480) ? 1 : 0;
}

// ---------------------------------------------------------------------------
// Weight prep: src[K][N] (ext dtype) -> dst[N][K] bf16, via 64x64 LDS tile.
// ---------------------------------------------------------------------------
__global__ __launch_bounds__(256) void wtrans_all(
    const void* sWq, const void* sWk, const void* sWv, const void* sWo,
    const void* cWq, const void* cWk, const void* cWv, const void* cWo,
    const void* fW1, const void* fW2,
    ushort_t* __restrict__ wb, const int* __restrict__ dflag)
{
    const void* src; ushort_t* dst; int Kd, Nd;
    switch (blockIdx.z) {
        case 0: src = sWq; dst = wb + 0;       Kd = 512;  Nd = 512;  break;
        case 1: src = sWk; dst = wb + 262144;  Kd = 512;  Nd = 512;  break;
        case 2: src = sWv; dst = wb + 524288;  Kd = 512;  Nd = 512;  break;
        case 3: src = sWo; dst = wb + 786432;  Kd = 512;  Nd = 512;  break;
        case 4: src = cWq; dst = wb + 1048576; Kd = 512;  Nd = 512;  break;
        case 5: src = cWk; dst = wb + 1310720; Kd = 512;  Nd = 512;  break;
        case 6: src = cWv; dst = wb + 1572864; Kd = 512;  Nd = 512;  break;
        case 7: src = cWo; dst = wb + 1835008; Kd = 512;  Nd = 512;  break;
        case 8: src = fW1; dst = wb + 2097152; Kd = 512;  Nd = 2048; break;
        default:src = fW2; dst = wb + 3145728; Kd = 2048; Nd = 512;  break;
    }
    const int k0 = blockIdx.x * 64, n0 = blockIdx.y * 64;
    if (k0 >= Kd || n0 >= Nd) return;
    const bool f32 = (dflag[0] == 0);
    __shared__ ushort_t T[64][65];
    const int tid = threadIdx.x;
#pragma unroll
    for (int i = 0; i < 16; ++i) {
        int j = i * 256 + tid;
        int r = j >> 6, c = j & 63;
        float v = f32 ? ((const float*)src)[(size_t)(k0 + r) * Nd + n0 + c]
                      : bf2f(((const ushort_t*)src)[(size_t)(k0 + r) * Nd + n0 + c]);
        T[r][c] = f2bf(v);
    }
    __syncthreads();
#pragma unroll
    for (int i = 0; i < 16; ++i) {
        int j = i * 256 + tid;
        int n = j >> 6, k = j & 63;
        dst[(size_t)(n0 + n) * Kd + k0 + k] = T[k][n];
    }
}

// activations tgt/mem -> bf16 (grid.x=2048, grid.y=2)
__global__ __launch_bounds__(256) void conv_act(
    const void* __restrict__ t, const void* __restrict__ m,
    ushort_t* __restrict__ td, ushort_t* __restrict__ md,
    const int* __restrict__ dflag)
{
    const bool f32 = (dflag[0] == 0);
    const void* src = blockIdx.y ? m : t;
    ushort_t* dst = blockIdx.y ? md : td;
    const int i = (blockIdx.x * 256 + threadIdx.x) * 4;
    if (f32) {
        float4 v = *(const float4*)((const float*)src + i);
        ushort_t o[4] = { f2bf(v.x), f2bf(v.y), f2bf(v.z), f2bf(v.w) };
        *(uint2*)(dst + i) = *(const uint2*)o;
    } else {
        *(uint2*)(dst + i) = *(const uint2*)((const ushort_t*)src + i);
    }
}

// all biases -> packed f32 [6656]; grid 26 x 256
__global__ __launch_bounds__(256) void prep_bias(
    const void* sbq, const void* sbk, const void* sbv, const void* sbo,
    const void* cbq, const void* cbk, const void* cbv, const void* cbo,
    const void* fb1, const void* fb2,
    float* __restrict__ dst, const int* __restrict__ dflag)
{
    const bool f32 = (dflag[0] == 0);
    const int i = blockIdx.x * 256 + threadIdx.x;
    if (i >= 6656) return;
    const void* src; int off;
    if      (i < 512)  { src = sbq; off = i; }
    else if (i < 1024) { src = sbk; off = i - 512; }
    else if (i < 1536) { src = sbv; off = i - 1024; }
    else if (i < 2048) { src = sbo; off = i - 1536; }
    else if (i < 2560) { src = cbq; off = i - 2048; }
    else if (i < 3072) { src = cbk; off = i - 2560; }
    else if (i < 3584) { src = cbv; off = i - 3072; }
    else if (i < 4096) { src = cbo; off = i - 3584; }
    else if (i < 6144) { src = fb1; off = i - 4096; }
    else               { src = fb2; off = i - 6144; }
    dst[i] = f32 ? ((const float*)src)[off] : bf2f(((const ushort_t*)src)[off]);
}

// ---------------------------------------------------------------------------
// GEMM: C[M][N] = act(A[M][K] @ Wt[N][K]^T + bias). 128x128 tile, BK=64,
// XOR-swizzled global_load_lds staging (conflict-free b128 frag reads).
// Dual-A: blockIdx.y < ySplit reads A1, else A2 (merges the two cross-attn
// projections into one dispatch; pass A1==A2, ySplit=0 otherwise).
// ---------------------------------------------------------------------------
template<typename OutT, bool RELU>
__global__ __launch_bounds__(256) void gemm_tn(
    const ushort_t* __restrict__ A1, const ushort_t* __restrict__ A2,
    int ySplit, int lda,
    const ushort_t* __restrict__ Wt, int ldw,
    const float* __restrict__ bias,
    OutT* __restrict__ C, int ldc, int K)
{
    __shared__ ushort_t As[128][64];
    __shared__ ushort_t Bs[128][64];
    const int tid = threadIdx.x;
    const int wave = tid >> 6, lane = tid & 63;
    const int quad = lane >> 4, l16 = lane & 15;
    const int m0 = blockIdx.x * 128, n0 = blockIdx.y * 128;
    const int wm = (wave >> 1) * 64, wn = (wave & 1) * 64;
    const ushort_t* A = (((int)blockIdx.y) < ySplit) ? A1 : A2;

    float4v acc[4][4];
#pragma unroll
    for (int mi = 0; mi < 4; ++mi)
#pragma unroll
        for (int ni = 0; ni < 4; ++ni) {
            acc[mi][ni][0] = 0.f; acc[mi][ni][1] = 0.f;
            acc[mi][ni][2] = 0.f; acc[mi][ni][3] = 0.f;
        }

    const int lr = lane >> 3;                      // 0..7 row within 8-row slab
    const int lcsw = ((lane & 7) ^ lr) * 8;        // swizzled k-chunk source
    const ushort_t* aptr = A  + (size_t)(m0 + wave * 8 + lr) * lda + lcsw;
    const ushort_t* bptr = Wt + (size_t)(n0 + wave * 8 + lr) * ldw + lcsw;
    ushort_t* asl = &As[wave * 8][0];              // wave-uniform LDS base
    ushort_t* bsl = &Bs[wave * 8][0];
    const int xsw = (l16 & 7);                     // frag-read XOR key (= r&7)

    for (int k0 = 0; k0 < K; k0 += 64) {
#pragma unroll
        for (int j = 0; j < 4; ++j) {
            gll16(aptr + (size_t)(j * 32) * lda, asl + j * 32 * 64);
            gll16(bptr + (size_t)(j * 32) * ldw, bsl + j * 32 * 64);
        }
        aptr += 64; bptr += 64;
        __syncthreads();

#pragma unroll
        for (int ks = 0; ks < 2; ++ks) {
            const int ca = ((quad + ks * 4) ^ xsw) * 8;
            short8 af[4], bfr[4];
#pragma unroll
            for (int mi = 0; mi < 4; ++mi)
                af[mi] = *(const short8*)(&As[wm + mi * 16 + l16][ca]);
#pragma unroll
            for (int ni = 0; ni < 4; ++ni)
                bfr[ni] = *(const short8*)(&Bs[wn + ni * 16 + l16][ca]);
#pragma unroll
            for (int mi = 0; mi < 4; ++mi)
#pragma unroll
                for (int ni = 0; ni < 4; ++ni)
                    acc[mi][ni] = __builtin_amdgcn_mfma_f32_16x16x32_bf16(
                        af[mi], bfr[ni], acc[mi][ni], 0, 0, 0);
        }
        __syncthreads();
    }

#pragma unroll
    for (int ni = 0; ni < 4; ++ni) {
        const int col = n0 + wn + ni * 16 + l16;
        const float bv = bias[col];
#pragma unroll
        for (int mi = 0; mi < 4; ++mi)
#pragma unroll
            for (int r = 0; r < 4; ++r) {
                const int row = m0 + wm + mi * 16 + quad * 4 + r;
                float v = acc[mi][ni][r] + bv;
                if (RELU) v = fmaxf(v, 0.f);
                store_out(&C[(size_t)row * ldc + col], v);
            }
    }
}

// ---------------------------------------------------------------------------
// Flash attention (MFMA) over packed qkv [4096][1536]. Fixed-reference
// streaming softmax: p = 2^((s-16)*scale*log2e). Since O/l is invariant to
// the reference, this is exact as long as no overflow (needs s > ~720 to
// overflow f32 — impossible here; scores are O(10)). Removes per-tile max
// and sum shuffles, alpha, and accumulator rescale; l reduced once at end.
// O written in-place over Q (block-disjoint tiles).
// ---------------------------------------------------------------------------
__global__ __launch_bounds__(256) void attn_mfma(ushort_t* __restrict__ QKV)
{
    const int S = 1536;
    __shared__ ushort_t Qs[64][72];
    __shared__ ushort_t Ks[64][72];
    __shared__ ushort_t Vt[64][72];
    __shared__ ushort_t Ps[4][16][72];

    const int tid  = threadIdx.x;
    const int wave = tid >> 6, lane = tid & 63;
    const int quad = lane >> 4, l16 = lane & 15;
    const int qt = blockIdx.x, bh = blockIdx.y;
    const int b = bh >> 3, h = bh & 7;
    const size_t rowQ = (size_t)b * 1024 + qt * 64;
    const size_t kv0  = (size_t)b * 1024;

    {
        const int r = tid >> 2, c = (tid & 3) * 16;
        const ushort_t* src = QKV + (rowQ + r) * S + h * 64 + c;
        *(uint4*)(&Qs[r][c])     = *(const uint4*)(src);
        *(uint4*)(&Qs[r][c + 8]) = *(const uint4*)(src + 8);
    }
    __syncthreads();
    short8 qf[2];
    qf[0] = *(const short8*)(&Qs[wave * 16 + l16][quad * 8]);
    qf[1] = *(const short8*)(&Qs[wave * 16 + l16][32 + quad * 8]);

    const float CEXP = 0.125f * 1.44269504f;   // head-scale * log2(e)
    const float MREF = 16.0f * CEXP;           // fixed softmax reference
    float lsum[4];
    float4v oacc[4];
#pragma unroll
    for (int r = 0; r < 4; ++r) lsum[r] = 0.f;
#pragma unroll
    for (int n = 0; n < 4; ++n) { oacc[n][0]=0.f; oacc[n][1]=0.f; oacc[n][2]=0.f; oacc[n][3]=0.f; }

    for (int s0 = 0; s0 < 1024; s0 += 64) {
        __syncthreads();
        {
            const int r = tid >> 2, c = (tid & 3) * 16;
            const ushort_t* ksrc = QKV + (kv0 + s0 + r) * S + 512 + h * 64 + c;
            *(uint4*)(&Ks[r][c])     = *(const uint4*)(ksrc);
            *(uint4*)(&Ks[r][c + 8]) = *(const uint4*)(ksrc + 8);
            const ushort_t* vsrc = QKV + (kv0 + s0 + r) * S + 1024 + h * 64 + c;
            ushort_t ve[16];
            *(uint4*)(&ve[0]) = *(const uint4*)(vsrc);
            *(uint4*)(&ve[8]) = *(const uint4*)(vsrc + 8);
#pragma unroll
            for (int j = 0; j < 16; ++j) {
                const int d = c + j;
                const int cc = ((r >> 3) ^ (d >> 4)) & 7;
                Vt[d][cc * 8 + (r & 7)] = ve[j];
            }
        }
        __syncthreads();

        // QK^T
        float4v sc[4];
#pragma unroll
        for (int sb = 0; sb < 4; ++sb) {
            float4v z; z[0]=0.f; z[1]=0.f; z[2]=0.f; z[3]=0.f;
            short8 kf0 = *(const short8*)(&Ks[sb * 16 + l16][quad * 8]);
            short8 kf1 = *(const short8*)(&Ks[sb * 16 + l16][32 + quad * 8]);
            z = __builtin_amdgcn_mfma_f32_16x16x32_bf16(qf[0], kf0, z, 0, 0, 0);
            z = __builtin_amdgcn_mfma_f32_16x16x32_bf16(qf[1], kf1, z, 0, 0, 0);
            sc[sb] = z;
        }

        // streaming softmax, fixed reference
#pragma unroll
        for (int sb = 0; sb < 4; ++sb)
#pragma unroll
            for (int r = 0; r < 4; ++r) {
                float p = exp2f(fmaf(sc[sb][r], CEXP, -MREF));
                lsum[r] += p;
                Ps[wave][quad * 4 + r][sb * 16 + l16] = f2bf(p);
            }

        // PV
        short8 pf[2];
        pf[0] = *(const short8*)(&Ps[wave][l16][quad * 8]);
        pf[1] = *(const short8*)(&Ps[wave][l16][32 + quad * 8]);
#pragma unroll
        for (int n = 0; n < 4; ++n) {
#pragma unroll
            for (int kc = 0; kc < 2; ++kc) {
                const int cc = ((kc * 4 + quad) ^ n) & 7;
                short8 vf = *(const short8*)(&Vt[n * 16 + l16][cc * 8]);
                oacc[n] = __builtin_amdgcn_mfma_f32_16x16x32_bf16(pf[kc], vf, oacc[n], 0, 0, 0);
            }
        }
    }

    // single final l reduction across the 16 s-lanes of each quad-group
#pragma unroll
    for (int msk = 1; msk < 16; msk <<= 1)
#pragma unroll
        for (int r = 0; r < 4; ++r) lsum[r] += __shfl_xor(lsum[r], msk);
    float inv[4];
#pragma unroll
    for (int r = 0; r < 4; ++r) inv[r] = 1.f / lsum[r];
#pragma unroll
    for (int n = 0; n < 4; ++n)
#pragma unroll
        for (int r = 0; r < 4; ++r) {
            const size_t row = rowQ + wave * 16 + quad * 4 + r;
            QKV[row * S + h * 64 + n * 16 + l16] = f2bf(oacc[n][r] * inv[r]);
        }
}

// ---------------------------------------------------------------------------
// LayerNorm over E=512, wave-shuffle reductions (2 barriers).
// ---------------------------------------------------------------------------
template<bool RES_EXT, bool DELTA_F32, bool OUT_FLAG>
__global__ __launch_bounds__(256) void ln_kernel(
    const void* __restrict__ res, const void* __restrict__ delta,
    const void* __restrict__ g, const void* __restrict__ be,
    void* __restrict__ out, const int* __restrict__ dflag)
{
    const int E = 512;
    const bool extf32 = (dflag[0] == 0);
    const int row = blockIdx.x, tid = threadIdx.x;
    const int wave = tid >> 6, lane = tid & 63;
    const size_t base = (size_t)row * E;
    const int i0 = tid, i1 = tid + 256;

    float r0, r1;
    if (RES_EXT && extf32) {
        r0 = ((const float*)res)[base + i0];
        r1 = ((const float*)res)[base + i1];
    } else {
        r0 = bf2f(((const ushort_t*)res)[base + i0]);
        r1 = bf2f(((const ushort_t*)res)[base + i1]);
    }
    float d0v, d1v;
    if (DELTA_F32) {
        d0v = ((const float*)delta)[base + i0];
        d1v = ((const float*)delta)[base + i1];
    } else {
        d0v = bf2f(((const ushort_t*)delta)[base + i0]);
        d1v = bf2f(((const ushort_t*)delta)[base + i1]);
    }
    float x0 = r0 + d0v, x1 = r1 + d1v;

    __shared__ float red8[8];
    float s = x0 + x1;
#pragma unroll
    for (int m = 1; m < 64; m <<= 1) s += __shfl_xor(s, m);
    if (lane == 0) red8[wave] = s;
    __syncthreads();
    float mean = (red8[0] + red8[1] + red8[2] + red8[3]) * (1.0f / 512.0f);
    float dd0 = x0 - mean, dd1 = x1 - mean;
    float v = dd0 * dd0 + dd1 * dd1;
#pragma unroll
    for (int m = 1; m < 64; m <<= 1) v += __shfl_xor(v, m);
    if (lane == 0) red8[4 + wave] = v;
    __syncthreads();
    float rstd = rsqrtf((red8[4] + red8[5] + red8[6] + red8[7]) * (1.0f / 512.0f) + 1e-5f);

    float g0, g1v, b0, b1;
    if (extf32) {
        g0 = ((const float*)g)[i0];  g1v = ((const float*)g)[i1];
        b0 = ((const float*)be)[i0]; b1  = ((const float*)be)[i1];
    } else {
        g0 = bf2f(((const ushort_t*)g)[i0]);  g1v = bf2f(((const ushort_t*)g)[i1]);
        b0 = bf2f(((const ushort_t*)be)[i0]); b1  = bf2f(((const ushort_t*)be)[i1]);
    }
    float y0 = dd0 * rstd * g0 + b0;
    float y1 = dd1 * rstd * g1v + b1;
    if (OUT_FLAG && extf32) {
        ((float*)out)[base + i0] = y0; ((float*)out)[base + i1] = y1;
    } else {
        ((ushort_t*)out)[base + i0] = f2bf(y0);
        ((ushort_t*)out)[base + i1] = f2bf(y1);
    }
}

// ---------------------------------------------------------------------------
// Workspace (~36.3 MiB):
//   [ 0 ..12M) qkv bf16 [4096][1536]   } FFN phase: hb bf16 [4096][2048]
//   [12M..16M) po  bf16 [4096][512]    }   occupies [0..16M)
//   [16M..20M) xb  bf16 [4096][512]  (residual, live through FFN)
//   [20M..24M) tb  bf16 (tgt)   } FFN phase: of f32 [4096][512] at [20..28M)
//   [24M..28M) mb  bf16 (mem)   }
//   [28M..36M) wb  bf16 transposed weights
//   [36M..]    pb  f32 packed biases; dflag at +256K
// ---------------------------------------------------------------------------

extern "C" void kernel_launch(void* const* d_in, const int* in_sizes, int n_in,
                              void* d_out, int out_size, void* d_ws, size_t ws_size,
                              hipStream_t stream) {
    const void* tgt = d_in[0];
    const void* mem = d_in[1];
    const void* sWq = d_in[2];  const void* sWk = d_in[3];
    const void* sWv = d_in[4];  const void* sWo = d_in[5];
    const void* cWq = d_in[6];  const void* cWk = d_in[7];
    const void* cWv = d_in[8];  const void* cWo = d_in[9];
    const void* sbq = d_in[10]; const void* sbk = d_in[11];
    const void* sbv = d_in[12]; const void* sbo = d_in[13];
    const void* cbq = d_in[14]; const void* cbk = d_in[15];
    const void* cbv = d_in[16]; const void* cbo = d_in[17];
    const void* fW1 = d_in[18]; const void* fb1 = d_in[19];
    const void* fW2 = d_in[20]; const void* fb2 = d_in[21];
    const void* g1  = d_in[22]; const void* g2  = d_in[23];
    const void* g3  = d_in[24];
    const void* be1 = d_in[25]; const void* be2 = d_in[26];
    const void* be3 = d_in[27];

    char* ws = (char*)d_ws;
    const size_t MB = 1048576;
    ushort_t* qkv = (ushort_t*)(ws + 0 * MB);
    ushort_t* hb  = (ushort_t*)(ws + 0 * MB);    // FFN hidden [4096][2048]
    ushort_t* po  = (ushort_t*)(ws + 12 * MB);
    ushort_t* xb  = (ushort_t*)(ws + 16 * MB);
    ushort_t* tb  = (ushort_t*)(ws + 20 * MB);
    ushort_t* mb  = (ushort_t*)(ws + 24 * MB);
    float*    of  = (float*)   (ws + 20 * MB);   // FFN out f32 [4096][512]
    ushort_t* wb  = (ushort_t*)(ws + 28 * MB);
    float*    pb  = (float*)   (ws + 36 * MB);
    int*   dflag  = (int*)     (ws + 36 * MB + 262144);

    const ushort_t* sWqkv_t = wb + 0;
    const ushort_t* sWo_t   = wb + 786432;
    const ushort_t* cWqkv_t = wb + 1048576;   // cWq_t|cWk_t|cWv_t contiguous
    const ushort_t* cWo_t   = wb + 1835008;
    const ushort_t* fW1_t   = wb + 2097152;
    const ushort_t* fW2_t   = wb + 3145728;

    dim3 blk(256);

    // ---- prep ----
    detect_dtype<<<dim3(1), blk, 0, stream>>>((const ushort_t*)tgt, dflag);
    wtrans_all<<<dim3(32, 32, 10), blk, 0, stream>>>(sWq, sWk, sWv, sWo, cWq, cWk, cWv, cWo, fW1, fW2, wb, dflag);
    conv_act<<<dim3(2048, 2), blk, 0, stream>>>(tgt, mem, tb, mb, dflag);
    prep_bias<<<dim3(26), blk, 0, stream>>>(sbq, sbk, sbv, sbo, cbq, cbk, cbv, cbo, fb1, fb2, pb, dflag);

    dim3 gattn(16, 32);

    // ---- self-attention ----
    gemm_tn<ushort_t, false><<<dim3(32, 12), blk, 0, stream>>>(tb, tb, 0, 512, sWqkv_t, 512, pb + 0, qkv, 1536, 512);
    attn_mfma<<<gattn, blk, 0, stream>>>(qkv);
    gemm_tn<ushort_t, false><<<dim3(32, 4), blk, 0, stream>>>(qkv, qkv, 0, 1536, sWo_t, 512, pb + 1536, po, 512, 512);
    ln_kernel<true, false, false><<<dim3(4096), blk, 0, stream>>>(tgt, po, g1, be1, xb, dflag);

    // ---- cross-attention (Q-proj and KV-proj fused into one dispatch) ----
    gemm_tn<ushort_t, false><<<dim3(32, 12), blk, 0, stream>>>(xb, mb, 4, 512, cWqkv_t, 512, pb + 2048, qkv, 1536, 512);
    attn_mfma<<<gattn, blk, 0, stream>>>(qkv);
    gemm_tn<ushort_t, false><<<dim3(32, 4), blk, 0, stream>>>(qkv, qkv, 0, 1536, cWo_t, 512, pb + 3584, po, 512, 512);
    ln_kernel<false, false, false><<<dim3(4096), blk, 0, stream>>>(xb, po, g2, be2, xb, dflag);

    // ---- FFN: full-width, single pass each ----
    gemm_tn<ushort_t, true><<<dim3(32, 16), blk, 0, stream>>>(xb, xb, 0, 512, fW1_t, 512, pb + 4096, hb, 2048, 512);
    gemm_tn<float, false><<<dim3(32, 4), blk, 0, stream>>>(hb, hb, 0, 2048, fW2_t, 2048, pb + 6144, of, 512, 2048);
    ln_kernel<false, true, true><<<dim3(4096), blk, 0, stream>>>(xb, of, g3, be3, d_out, dflag);
}

// Round 9
// 308.557 us; speedup vs baseline: 7.5043x; 1.0470x over previous
//
#include <hip/hip_runtime.h>

typedef unsigned short ushort_t;
typedef short short8 __attribute__((ext_vector_type(8)));
typedef float float4v __attribute__((ext_vector_type(4)));

__device__ __forceinline__ float bf2f(ushort_t u) {
    union { unsigned int i; float f; } x; x.i = ((unsigned int)u) << 16; return x.f;
}
__device__ __forceinline__ ushort_t f2bf(float f) {
    unsigned int u = __float_as_uint(f);
    unsigned int r = (u + 0x7FFFu + ((u >> 16) & 1u)) >> 16;
    return (ushort_t)r;
}
__device__ __forceinline__ void store_out(float* p, float v) { *p = v; }
__device__ __forceinline__ void store_out(ushort_t* p, float v) { *p = f2bf(v); }

// async global->LDS 16B/lane; lds ptr must be wave-uniform base (lane*16 auto)
__device__ __forceinline__ void gll16(const ushort_t* g, ushort_t* l) {
    __builtin_amdgcn_global_load_lds(
        (const __attribute__((address_space(1))) void*)g,
        (__attribute__((address_space(3))) void*)l, 16, 0, 0);
}

// ---------------------------------------------------------------------------
// Input-dtype detection. flag=1 -> inputs bf16; flag=0 -> inputs f32.
// ---------------------------------------------------------------------------
__global__ void detect_dtype(const ushort_t* __restrict__ tgt, int* __restrict__ flag) {
    __shared__ int red[256];
    const int tid = threadIdx.x;
    int p = 0;
    for (int i = tid; i < 512; i += 256) {
        ushort_t u = tgt[i];
        int e = (u >> 7) & 0xFF;
        if (u == 0 || (e >= 100 && e <= 140)) ++p;
    }
    red[tid] = p; __syncthreads();
    for (int off = 128; off > 0; off >>= 1) {
        if (tid < off) red[tid] += red[tid + off];
        __syncthreads();
    }
    if (tid == 0) flag[0] = (red[0] >= 480) ? 1 : 0;
}

// ---------------------------------------------------------------------------
// Weight prep: src[K][N] (ext dtype) -> dst[N][K] bf16, via 64x64 LDS tile.
// ---------------------------------------------------------------------------
__global__ __launch_bounds__(256) void wtrans_all(
    const void* sWq, const void* sWk, const void* sWv, const void* sWo,
    const void* cWq, const void* cWk, const void* cWv, const void* cWo,
    const void* fW1, const void* fW2,
    ushort_t* __restrict__ wb, const int* __restrict__ dflag)
{
    const void* src; ushort_t* dst; int Kd, Nd;
    switch (blockIdx.z) {
        case 0: src = sWq; dst = wb + 0;       Kd = 512;  Nd = 512;  break;
        case 1: src = sWk; dst = wb + 262144;  Kd = 512;  Nd = 512;  break;
        case 2: src = sWv; dst = wb + 524288;  Kd = 512;  Nd = 512;  break;
        case 3: src = sWo; dst = wb + 786432;  Kd = 512;  Nd = 512;  break;
        case 4: src = cWq; dst = wb + 1048576; Kd = 512;  Nd = 512;  break;
        case 5: src = cWk; dst = wb + 1310720; Kd = 512;  Nd = 512;  break;
        case 6: src = cWv; dst = wb + 1572864; Kd = 512;  Nd = 512;  break;
        case 7: src = cWo; dst = wb + 1835008; Kd = 512;  Nd = 512;  break;
        case 8: src = fW1; dst = wb + 2097152; Kd = 512;  Nd = 2048; break;
        default:src = fW2; dst = wb + 3145728; Kd = 2048; Nd = 512;  break;
    }
    const int k0 = blockIdx.x * 64, n0 = blockIdx.y * 64;
    if (k0 >= Kd || n0 >= Nd) return;
    const bool f32 = (dflag[0] == 0);
    __shared__ ushort_t T[64][65];
    const int tid = threadIdx.x;
#pragma unroll
    for (int i = 0; i < 16; ++i) {
        int j = i * 256 + tid;
        int r = j >> 6, c = j & 63;
        float v = f32 ? ((const float*)src)[(size_t)(k0 + r) * Nd + n0 + c]
                      : bf2f(((const ushort_t*)src)[(size_t)(k0 + r) * Nd + n0 + c]);
        T[r][c] = f2bf(v);
    }
    __syncthreads();
#pragma unroll
    for (int i = 0; i < 16; ++i) {
        int j = i * 256 + tid;
        int n = j >> 6, k = j & 63;
        dst[(size_t)(n0 + n) * Kd + k0 + k] = T[k][n];
    }
}

// activations tgt/mem -> bf16 (grid.x=2048, grid.y=2)
__global__ __launch_bounds__(256) void conv_act(
    const void* __restrict__ t, const void* __restrict__ m,
    ushort_t* __restrict__ td, ushort_t* __restrict__ md,
    const int* __restrict__ dflag)
{
    const bool f32 = (dflag[0] == 0);
    const void* src = blockIdx.y ? m : t;
    ushort_t* dst = blockIdx.y ? md : td;
    const int i = (blockIdx.x * 256 + threadIdx.x) * 4;
    if (f32) {
        float4 v = *(const float4*)((const float*)src + i);
        ushort_t o[4] = { f2bf(v.x), f2bf(v.y), f2bf(v.z), f2bf(v.w) };
        *(uint2*)(dst + i) = *(const uint2*)o;
    } else {
        *(uint2*)(dst + i) = *(const uint2*)((const ushort_t*)src + i);
    }
}

// all biases -> packed f32 [6656]; grid 26 x 256
__global__ __launch_bounds__(256) void prep_bias(
    const void* sbq, const void* sbk, const void* sbv, const void* sbo,
    const void* cbq, const void* cbk, const void* cbv, const void* cbo,
    const void* fb1, const void* fb2,
    float* __restrict__ dst, const int* __restrict__ dflag)
{
    const bool f32 = (dflag[0] == 0);
    const int i = blockIdx.x * 256 + threadIdx.x;
    if (i >= 6656) return;
    const void* src; int off;
    if      (i < 512)  { src = sbq; off = i; }
    else if (i < 1024) { src = sbk; off = i - 512; }
    else if (i < 1536) { src = sbv; off = i - 1024; }
    else if (i < 2048) { src = sbo; off = i - 1536; }
    else if (i < 2560) { src = cbq; off = i - 2048; }
    else if (i < 3072) { src = cbk; off = i - 2560; }
    else if (i < 3584) { src = cbv; off = i - 3072; }
    else if (i < 4096) { src = cbo; off = i - 3584; }
    else if (i < 6144) { src = fb1; off = i - 4096; }
    else               { src = fb2; off = i - 6144; }
    dst[i] = f32 ? ((const float*)src)[off] : bf2f(((const ushort_t*)src)[off]);
}

// ---------------------------------------------------------------------------
// GEMM: C[M][N] = act(A[M][K] @ Wt[N][K]^T + bias). BM=128, BN templated
// (128 or 64), BK=64, XOR-swizzled global_load_lds staging (conflict-free
// b128 frag reads). BN=64 doubles block count for N=512 outputs so all 256
// CUs are covered (BN=128 there leaves half the chip idle). Dual-A via
// ySplit merges the cross-attn Q/KV projections into one dispatch.
// ---------------------------------------------------------------------------
template<typename OutT, bool RELU, int BN>
__global__ __launch_bounds__(256) void gemm_tn(
    const ushort_t* __restrict__ A1, const ushort_t* __restrict__ A2,
    int ySplit, int lda,
    const ushort_t* __restrict__ Wt, int ldw,
    const float* __restrict__ bias,
    OutT* __restrict__ C, int ldc, int K)
{
    constexpr int MI = (BN == 128) ? 4 : 2;   // 16-row m-tiles per wave
    __shared__ ushort_t As[128][64];
    __shared__ ushort_t Bs[BN][64];
    const int tid = threadIdx.x;
    const int wave = tid >> 6, lane = tid & 63;
    const int quad = lane >> 4, l16 = lane & 15;
    const int m0 = blockIdx.x * 128, n0 = blockIdx.y * BN;
    const int wm = (BN == 128) ? (wave >> 1) * 64 : wave * 32;
    const int wn = (BN == 128) ? (wave & 1) * 64 : 0;
    const ushort_t* A = (((int)blockIdx.y) < ySplit) ? A1 : A2;

    float4v acc[MI][4];
#pragma unroll
    for (int mi = 0; mi < MI; ++mi)
#pragma unroll
        for (int ni = 0; ni < 4; ++ni) {
            acc[mi][ni][0] = 0.f; acc[mi][ni][1] = 0.f;
            acc[mi][ni][2] = 0.f; acc[mi][ni][3] = 0.f;
        }

    const int lr = lane >> 3;                      // 0..7 row within 8-row slab
    const int lcsw = ((lane & 7) ^ lr) * 8;        // swizzled k-chunk source
    const ushort_t* aptr = A  + (size_t)(m0 + wave * 8 + lr) * lda + lcsw;
    const ushort_t* bptr = Wt + (size_t)(n0 + wave * 8 + lr) * ldw + lcsw;
    ushort_t* asl = &As[wave * 8][0];              // wave-uniform LDS base
    ushort_t* bsl = &Bs[wave * 8][0];
    const int xsw = (l16 & 7);                     // frag-read XOR key (= r&7)

    for (int k0 = 0; k0 < K; k0 += 64) {
#pragma unroll
        for (int j = 0; j < 4; ++j)
            gll16(aptr + (size_t)(j * 32) * lda, asl + j * 32 * 64);
#pragma unroll
        for (int j = 0; j < BN / 32; ++j)
            gll16(bptr + (size_t)(j * 32) * ldw, bsl + j * 32 * 64);
        aptr += 64; bptr += 64;
        __syncthreads();

#pragma unroll
        for (int ks = 0; ks < 2; ++ks) {
            const int ca = ((quad + ks * 4) ^ xsw) * 8;
            short8 af[MI], bfr[4];
#pragma unroll
            for (int mi = 0; mi < MI; ++mi)
                af[mi] = *(const short8*)(&As[wm + mi * 16 + l16][ca]);
#pragma unroll
            for (int ni = 0; ni < 4; ++ni)
                bfr[ni] = *(const short8*)(&Bs[wn + ni * 16 + l16][ca]);
#pragma unroll
            for (int mi = 0; mi < MI; ++mi)
#pragma unroll
                for (int ni = 0; ni < 4; ++ni)
                    acc[mi][ni] = __builtin_amdgcn_mfma_f32_16x16x32_bf16(
                        af[mi], bfr[ni], acc[mi][ni], 0, 0, 0);
        }
        __syncthreads();
    }

#pragma unroll
    for (int ni = 0; ni < 4; ++ni) {
        const int col = n0 + wn + ni * 16 + l16;
        const float bv = bias[col];
#pragma unroll
        for (int mi = 0; mi < MI; ++mi)
#pragma unroll
            for (int r = 0; r < 4; ++r) {
                const int row = m0 + wm + mi * 16 + quad * 4 + r;
                float v = acc[mi][ni][r] + bv;
                if (RELU) v = fmaxf(v, 0.f);
                store_out(&C[(size_t)row * ldc + col], v);
            }
    }
}

// ---------------------------------------------------------------------------
// Flash attention (MFMA) over packed qkv [4096][1536]. Fixed-reference
// streaming softmax (exact for O/l; overflow needs s>~700, impossible here).
// V staged transposed via s-PAIR packed u32 LDS writes (8 b32 instead of
// 16 b16 per thread per tile; XOR-swizzled chunks keep (s,s+1) adjacent).
// O written in-place over Q (block-disjoint tiles).
// ---------------------------------------------------------------------------
__global__ __launch_bounds__(256) void attn_mfma(ushort_t* __restrict__ QKV)
{
    const int S = 1536;
    __shared__ ushort_t Qs[64][72];
    __shared__ ushort_t Ks[64][72];
    __shared__ ushort_t Vt[64][72];
    __shared__ ushort_t Ps[4][16][72];

    const int tid  = threadIdx.x;
    const int wave = tid >> 6, lane = tid & 63;
    const int quad = lane >> 4, l16 = lane & 15;
    const int qt = blockIdx.x, bh = blockIdx.y;
    const int b = bh >> 3, h = bh & 7;
    const size_t rowQ = (size_t)b * 1024 + qt * 64;
    const size_t kv0  = (size_t)b * 1024;

    {
        const int r = tid >> 2, c = (tid & 3) * 16;
        const ushort_t* src = QKV + (rowQ + r) * S + h * 64 + c;
        *(uint4*)(&Qs[r][c])     = *(const uint4*)(src);
        *(uint4*)(&Qs[r][c + 8]) = *(const uint4*)(src + 8);
    }
    __syncthreads();
    short8 qf[2];
    qf[0] = *(const short8*)(&Qs[wave * 16 + l16][quad * 8]);
    qf[1] = *(const short8*)(&Qs[wave * 16 + l16][32 + quad * 8]);

    const float CEXP = 0.125f * 1.44269504f;   // head-scale * log2(e)
    const float MREF = 16.0f * CEXP;           // fixed softmax reference
    float lsum[4];
    float4v oacc[4];
#pragma unroll
    for (int r = 0; r < 4; ++r) lsum[r] = 0.f;
#pragma unroll
    for (int n = 0; n < 4; ++n) { oacc[n][0]=0.f; oacc[n][1]=0.f; oacc[n][2]=0.f; oacc[n][3]=0.f; }

    for (int s0 = 0; s0 < 1024; s0 += 64) {
        __syncthreads();
        {   // K tile, direct
            const int r = tid >> 2, c = (tid & 3) * 16;
            const ushort_t* ksrc = QKV + (kv0 + s0 + r) * S + 512 + h * 64 + c;
            *(uint4*)(&Ks[r][c])     = *(const uint4*)(ksrc);
            *(uint4*)(&Ks[r][c + 8]) = *(const uint4*)(ksrc + 8);
        }
        {   // V tile, transposed: one s-pair x 8 d per thread, packed u32
            const int sp = tid >> 3, dc = (tid & 7) * 8;
            const int r0 = sp * 2;
            const ushort_t* v0 = QKV + (kv0 + s0 + r0) * S + 1024 + h * 64 + dc;
            uint4 a = *(const uint4*)v0;
            uint4 bq = *(const uint4*)(v0 + S);
            const ushort_t* ae = (const ushort_t*)&a;
            const ushort_t* be = (const ushort_t*)&bq;
            const int rg = r0 >> 3, rof = r0 & 7;
#pragma unroll
            for (int j = 0; j < 8; ++j) {
                const int d = dc + j;
                const int cc = (rg ^ (d >> 4)) & 7;
                *(unsigned int*)(&Vt[d][cc * 8 + rof]) =
                    (unsigned int)ae[j] | ((unsigned int)be[j] << 16);
            }
        }
        __syncthreads();

        // QK^T
        float4v sc[4];
#pragma unroll
        for (int sb = 0; sb < 4; ++sb) {
            float4v z; z[0]=0.f; z[1]=0.f; z[2]=0.f; z[3]=0.f;
            short8 kf0 = *(const short8*)(&Ks[sb * 16 + l16][quad * 8]);
            short8 kf1 = *(const short8*)(&Ks[sb * 16 + l16][32 + quad * 8]);
            z = __builtin_amdgcn_mfma_f32_16x16x32_bf16(qf[0], kf0, z, 0, 0, 0);
            z = __builtin_amdgcn_mfma_f32_16x16x32_bf16(qf[1], kf1, z, 0, 0, 0);
            sc[sb] = z;
        }

        // streaming softmax, fixed reference
#pragma unroll
        for (int sb = 0; sb < 4; ++sb)
#pragma unroll
            for (int r = 0; r < 4; ++r) {
                float p = exp2f(fmaf(sc[sb][r], CEXP, -MREF));
                lsum[r] += p;
                Ps[wave][quad * 4 + r][sb * 16 + l16] = f2bf(p);
            }

        // PV
        short8 pf[2];
        pf[0] = *(const short8*)(&Ps[wave][l16][quad * 8]);
        pf[1] = *(const short8*)(&Ps[wave][l16][32 + quad * 8]);
#pragma unroll
        for (int n = 0; n < 4; ++n) {
#pragma unroll
            for (int kc = 0; kc < 2; ++kc) {
                const int cc = ((kc * 4 + quad) ^ n) & 7;
                short8 vf = *(const short8*)(&Vt[n * 16 + l16][cc * 8]);
                oacc[n] = __builtin_amdgcn_mfma_f32_16x16x32_bf16(pf[kc], vf, oacc[n], 0, 0, 0);
            }
        }
    }

    // single final l reduction across the 16 s-lanes of each quad-group
#pragma unroll
    for (int msk = 1; msk < 16; msk <<= 1)
#pragma unroll
        for (int r = 0; r < 4; ++r) lsum[r] += __shfl_xor(lsum[r], msk);
    float inv[4];
#pragma unroll
    for (int r = 0; r < 4; ++r) inv[r] = 1.f / lsum[r];
#pragma unroll
    for (int n = 0; n < 4; ++n)
#pragma unroll
        for (int r = 0; r < 4; ++r) {
            const size_t row = rowQ + wave * 16 + quad * 4 + r;
            QKV[row * S + h * 64 + n * 16 + l16] = f2bf(oacc[n][r] * inv[r]);
        }
}

// ---------------------------------------------------------------------------
// LayerNorm over E=512, wave-shuffle reductions (2 barriers).
// ---------------------------------------------------------------------------
template<bool RES_EXT, bool DELTA_F32, bool OUT_FLAG>
__global__ __launch_bounds__(256) void ln_kernel(
    const void* __restrict__ res, const void* __restrict__ delta,
    const void* __restrict__ g, const void* __restrict__ be,
    void* __restrict__ out, const int* __restrict__ dflag)
{
    const int E = 512;
    const bool extf32 = (dflag[0] == 0);
    const int row = blockIdx.x, tid = threadIdx.x;
    const int wave = tid >> 6, lane = tid & 63;
    const size_t base = (size_t)row * E;
    const int i0 = tid, i1 = tid + 256;

    float r0, r1;
    if (RES_EXT && extf32) {
        r0 = ((const float*)res)[base + i0];
        r1 = ((const float*)res)[base + i1];
    } else {
        r0 = bf2f(((const ushort_t*)res)[base + i0]);
        r1 = bf2f(((const ushort_t*)res)[base + i1]);
    }
    float d0v, d1v;
    if (DELTA_F32) {
        d0v = ((const float*)delta)[base + i0];
        d1v = ((const float*)delta)[base + i1];
    } else {
        d0v = bf2f(((const ushort_t*)delta)[base + i0]);
        d1v = bf2f(((const ushort_t*)delta)[base + i1]);
    }
    float x0 = r0 + d0v, x1 = r1 + d1v;

    __shared__ float red8[8];
    float s = x0 + x1;
#pragma unroll
    for (int m = 1; m < 64; m <<= 1) s += __shfl_xor(s, m);
    if (lane == 0) red8[wave] = s;
    __syncthreads();
    float mean = (red8[0] + red8[1] + red8[2] + red8[3]) * (1.0f / 512.0f);
    float dd0 = x0 - mean, dd1 = x1 - mean;
    float v = dd0 * dd0 + dd1 * dd1;
#pragma unroll
    for (int m = 1; m < 64; m <<= 1) v += __shfl_xor(v, m);
    if (lane == 0) red8[4 + wave] = v;
    __syncthreads();
    float rstd = rsqrtf((red8[4] + red8[5] + red8[6] + red8[7]) * (1.0f / 512.0f) + 1e-5f);

    float g0, g1v, b0, b1;
    if (extf32) {
        g0 = ((const float*)g)[i0];  g1v = ((const float*)g)[i1];
        b0 = ((const float*)be)[i0]; b1  = ((const float*)be)[i1];
    } else {
        g0 = bf2f(((const ushort_t*)g)[i0]);  g1v = bf2f(((const ushort_t*)g)[i1]);
        b0 = bf2f(((const ushort_t*)be)[i0]); b1  = bf2f(((const ushort_t*)be)[i1]);
    }
    float y0 = dd0 * rstd * g0 + b0;
    float y1 = dd1 * rstd * g1v + b1;
    if (OUT_FLAG && extf32) {
        ((float*)out)[base + i0] = y0; ((float*)out)[base + i1] = y1;
    } else {
        ((ushort_t*)out)[base + i0] = f2bf(y0);
        ((ushort_t*)out)[base + i1] = f2bf(y1);
    }
}

// ---------------------------------------------------------------------------
// Workspace (~36.3 MiB):
//   [ 0 ..12M) qkv bf16 [4096][1536]   } FFN phase: hb bf16 [4096][2048]
//   [12M..16M) po  bf16 [4096][512]    }   occupies [0..16M)
//   [16M..20M) xb  bf16 [4096][512]  (residual, live through FFN)
//   [20M..24M) tb  bf16 (tgt)   } FFN phase: of f32 [4096][512] at [20..28M)
//   [24M..28M) mb  bf16 (mem)   }
//   [28M..36M) wb  bf16 transposed weights
//   [36M..]    pb  f32 packed biases; dflag at +256K
// ---------------------------------------------------------------------------

extern "C" void kernel_launch(void* const* d_in, const int* in_sizes, int n_in,
                              void* d_out, int out_size, void* d_ws, size_t ws_size,
                              hipStream_t stream) {
    const void* tgt = d_in[0];
    const void* mem = d_in[1];
    const void* sWq = d_in[2];  const void* sWk = d_in[3];
    const void* sWv = d_in[4];  const void* sWo = d_in[5];
    const void* cWq = d_in[6];  const void* cWk = d_in[7];
    const void* cWv = d_in[8];  const void* cWo = d_in[9];
    const void* sbq = d_in[10]; const void* sbk = d_in[11];
    const void* sbv = d_in[12]; const void* sbo = d_in[13];
    const void* cbq = d_in[14]; const void* cbk = d_in[15];
    const void* cbv = d_in[16]; const void* cbo = d_in[17];
    const void* fW1 = d_in[18]; const void* fb1 = d_in[19];
    const void* fW2 = d_in[20]; const void* fb2 = d_in[21];
    const void* g1  = d_in[22]; const void* g2  = d_in[23];
    const void* g3  = d_in[24];
    const void* be1 = d_in[25]; const void* be2 = d_in[26];
    const void* be3 = d_in[27];

    char* ws = (char*)d_ws;
    const size_t MB = 1048576;
    ushort_t* qkv = (ushort_t*)(ws + 0 * MB);
    ushort_t* hb  = (ushort_t*)(ws + 0 * MB);    // FFN hidden [4096][2048]
    ushort_t* po  = (ushort_t*)(ws + 12 * MB);
    ushort_t* xb  = (ushort_t*)(ws + 16 * MB);
    ushort_t* tb  = (ushort_t*)(ws + 20 * MB);
    ushort_t* mb  = (ushort_t*)(ws + 24 * MB);
    float*    of  = (float*)   (ws + 20 * MB);   // FFN out f32 [4096][512]
    ushort_t* wb  = (ushort_t*)(ws + 28 * MB);
    float*    pb  = (float*)   (ws + 36 * MB);
    int*   dflag  = (int*)     (ws + 36 * MB + 262144);

    const ushort_t* sWqkv_t = wb + 0;
    const ushort_t* sWo_t   = wb + 786432;
    const ushort_t* cWqkv_t = wb + 1048576;   // cWq_t|cWk_t|cWv_t contiguous
    const ushort_t* cWo_t   = wb + 1835008;
    const ushort_t* fW1_t   = wb + 2097152;
    const ushort_t* fW2_t   = wb + 3145728;

    dim3 blk(256);

    // ---- prep ----
    detect_dtype<<<dim3(1), blk, 0, stream>>>((const ushort_t*)tgt, dflag);
    wtrans_all<<<dim3(32, 32, 10), blk, 0, stream>>>(sWq, sWk, sWv, sWo, cWq, cWk, cWv, cWo, fW1, fW2, wb, dflag);
    conv_act<<<dim3(2048, 2), blk, 0, stream>>>(tgt, mem, tb, mb, dflag);
    prep_bias<<<dim3(26), blk, 0, stream>>>(sbq, sbk, sbv, sbo, cbq, cbk, cbv, cbo, fb1, fb2, pb, dflag);

    dim3 gattn(16, 32);

    // ---- self-attention ----
    gemm_tn<ushort_t, false, 128><<<dim3(32, 12), blk, 0, stream>>>(tb, tb, 0, 512, sWqkv_t, 512, pb + 0, qkv, 1536, 512);
    attn_mfma<<<gattn, blk, 0, stream>>>(qkv);
    gemm_tn<ushort_t, false, 64><<<dim3(32, 8), blk, 0, stream>>>(qkv, qkv, 0, 1536, sWo_t, 512, pb + 1536, po, 512, 512);
    ln_kernel<true, false, false><<<dim3(4096), blk, 0, stream>>>(tgt, po, g1, be1, xb, dflag);

    // ---- cross-attention (Q-proj and KV-proj fused into one dispatch) ----
    gemm_tn<ushort_t, false, 128><<<dim3(32, 12), blk, 0, stream>>>(xb, mb, 4, 512, cWqkv_t, 512, pb + 2048, qkv, 1536, 512);
    attn_mfma<<<gattn, blk, 0, stream>>>(qkv);
    gemm_tn<ushort_t, false, 64><<<dim3(32, 8), blk, 0, stream>>>(qkv, qkv, 0, 1536, cWo_t, 512, pb + 3584, po, 512, 512);
    ln_kernel<false, false, false><<<dim3(4096), blk, 0, stream>>>(xb, po, g2, be2, xb, dflag);

    // ---- FFN: full-width, single pass each ----
    gemm_tn<ushort_t, true, 128><<<dim3(32, 16), blk, 0, stream>>>(xb, xb, 0, 512, fW1_t, 512, pb + 4096, hb, 2048, 512);
    gemm_tn<float, false, 64><<<dim3(32, 8), blk, 0, stream>>>(hb, hb, 0, 2048, fW2_t, 2048, pb + 6144, of, 512, 2048);
    ln_kernel<false, true, true><<<dim3(4096), blk, 0, stream>>>(xb, of, g3, be3, d_out, dflag);
}